// Round 12
// baseline (713.289 us; speedup 1.0000x reference)
//
#include <hip/hip_runtime.h>
#include <hip/hip_bf16.h>
#include <float.h>
#include <math.h>

#define BB 4
#define N1 4096
#define NT 8192
#define CH 128
#define NBRS 18
#define ZSEL 2.35f
#define EQ 4096.0f     // e-quantum: 1/4096 score units
#define GQGAP 6        // certify gap (quanta)
#define GQCOV 3        // coverage margin (quanta)
#define QPB 256        // queries per block

typedef __attribute__((ext_vector_type(8))) short s16x8;
typedef __attribute__((ext_vector_type(16))) float f32x16;

__device__ inline unsigned short f2bf(float v) {
  unsigned u = __float_as_uint(v);
  unsigned r = (u + 0x7FFFu + ((u >> 16) & 1u)) >> 16;
  return (unsigned short)r;
}

__device__ inline unsigned mapf(float f) {
  unsigned u = __float_as_uint(f);
  return (u & 0x80000000u) ? ~u : (u | 0x80000000u);
}

#define INS12U(l, key0)                         \
  {                                             \
    unsigned nk = key0;                         \
    _Pragma("unroll")                           \
    for (int j = 0; j < 12; ++j) {              \
      bool sw = nk > l[j];                      \
      unsigned tv = l[j];                       \
      l[j] = sw ? nk : tv;                      \
      nk = sw ? tv : nk;                        \
    }                                           \
  }

// ---------------------------------------------------------------- transpose
__global__ __launch_bounds__(256) void transpose_k(const float* __restrict__ in,
                                                   float* __restrict__ out,
                                                   int rows, int cols) {
  int t = blockIdx.x * 256 + threadIdx.x;
  if (t < rows * cols) {
    int r = t / cols, c = t % cols;
    out[c * rows + r] = in[t];
  }
}

// ------------------------------------------------- concat x,y + squared norms
__global__ __launch_bounds__(256) void norms_concat_k(const float* __restrict__ x,
                                                      const float* __restrict__ y,
                                                      float* __restrict__ xy,
                                                      float* __restrict__ norms) {
  int w = (blockIdx.x * 256 + threadIdx.x) >> 6;  // global point id, 0..32767
  int lane = threadIdx.x & 63;
  int b = w >> 13, row = w & 8191;
  const float* src = (row < N1) ? (x + ((size_t)b * N1 + row) * CH)
                                : (y + ((size_t)b * N1 + (row - N1)) * CH);
  float2 v = *(const float2*)(src + lane * 2);
  *(float2*)(xy + (size_t)w * CH + lane * 2) = v;
  float s = v.x * v.x + v.y * v.y;
  for (int off = 32; off > 0; off >>= 1) s += __shfl_down(s, off);
  if (lane == 0) norms[w] = s;
}

// ---------------------------------------- build split-bf16 k-major candidate buf
__global__ __launch_bounds__(256) void cbt_k(const float* __restrict__ xy,
                                             unsigned short* __restrict__ cbt) {
  int t = blockIdx.x * 256 + threadIdx.x;  // 32768*16
  int u = t >> 15, p = t & 32767;
  const float* src = xy + (size_t)p * CH + u * 8;
  unsigned hw[4], lw[4];
#pragma unroll
  for (int j = 0; j < 4; ++j) {
    float v0 = src[2 * j], v1 = src[2 * j + 1];
    unsigned short h0 = f2bf(v0), h1 = f2bf(v1);
    float r0 = v0 - __uint_as_float((unsigned)h0 << 16);
    float r1 = v1 - __uint_as_float((unsigned)h1 << 16);
    unsigned short l0 = f2bf(r0), l1 = f2bf(r1);
    hw[j] = (unsigned)h0 | ((unsigned)h1 << 16);
    lw[j] = (unsigned)l0 | ((unsigned)l1 << 16);
  }
  *(uint4*)&cbt[((size_t)u * 32768 + p) * 8] = make_uint4(hw[0], hw[1], hw[2], hw[3]);
  *(uint4*)&cbt[((size_t)(u + 16) * 32768 + p) * 8] = make_uint4(lw[0], lw[1], lw[2], lw[3]);
}

// ----- MFMA knn: 256 queries/block (8 waves share one candidate stream) to
// halve L3 candidate traffic; per-lane sorted register top-12 collect;
// in-block certify tail. grid (16 qblk, 16 z), block 512.
__global__ __launch_bounds__(512, 2) void knn8_k(const unsigned short* __restrict__ cbt,
                                                 const float* __restrict__ norms,
                                                 int* __restrict__ nbr,
                                                 int* __restrict__ cntg,
                                                 unsigned* __restrict__ listA,
                                                 unsigned* __restrict__ listB,
                                                 unsigned short* __restrict__ fbl) {
  __shared__ unsigned short __align__(16) cst[2][32][32][8];  // 32.8 KB (dump area later)
  __shared__ float cn_s[2][32];
  __shared__ unsigned short cnt2[QPB][2];                     // 1 KB
  const int tid = threadIdx.x;          // 0..511
  const int qblk = blockIdx.x, z = blockIdx.y;
  const int b = z >> 2, combo = z & 3;
  const int qoff = (combo <= 1) ? 0 : N1;
  const int coff = (combo == 0 || combo == 3) ? 0 : N1;
  const int w = tid >> 6;               // wave 0..7
  const int cl = tid & 31;
  const int h = (tid >> 5) & 1;
  const int h4 = 4 * h;
  const int ql = w * 32 + cl;           // query-local 0..255
  const int q = qblk * QPB + ql;
  const size_t qp = (size_t)b * NT + qoff + q;
  const size_t cb0 = (size_t)b * NT + coff;

  const s16x8* cv = (const s16x8*)cbt;
  s16x8 bh[8], bl[8];
#pragma unroll
  for (int s = 0; s < 8; ++s) {
    bh[s] = cv[(size_t)(2 * s + h) * 32768 + qp];
    bl[s] = cv[(size_t)(16 + 2 * s + h) * 32768 + qp];
  }

  const float nq = norms[qp];
  const float Tc = 128.f - ZSEL * sqrtf(256.f + 4.f * nq);
  int cnt = 0;
  unsigned lA[12];
#pragma unroll
  for (int j = 0; j < 12; ++j) lA[j] = 0u;

  // staging: 512 threads, each loads rows su and su+16 (32B total) per chunk
  const int su = tid >> 5;   // 0..15
  const int sc = tid & 31;
  const char* p0 = (const char*)&cbt[((size_t)(su) * 32768 + cb0 + sc) * 8];
  const char* p1 = (const char*)&cbt[((size_t)(16 + su) * 32768 + cb0 + sc) * 8];
  const float* pn = norms + cb0 + tid;  // valid when tid<32

  uint4 st0, st1; float cnreg = 0.f;
  st0 = *(const uint4*)p0; p0 += 512;
  st1 = *(const uint4*)p1; p1 += 512;
  if (tid < 32) { cnreg = *pn; pn += 32; }
  *(uint4*)&cst[0][su][sc][0] = st0;
  *(uint4*)&cst[0][16 + su][sc][0] = st1;
  if (tid < 32) cn_s[0][tid] = cnreg;
  __syncthreads();

  int buf = 0;
  for (int t = 0; t < 128; ++t) {
    if (t < 127) {
      st0 = *(const uint4*)p0; p0 += 512;
      st1 = *(const uint4*)p1; p1 += 512;
      if (tid < 32) { cnreg = *pn; pn += 32; }
    }
    f32x16 acc = {0.f,0.f,0.f,0.f,0.f,0.f,0.f,0.f,0.f,0.f,0.f,0.f,0.f,0.f,0.f,0.f};
#pragma unroll
    for (int s = 0; s < 8; ++s) {
      s16x8 a0 = *(const s16x8*)&cst[buf][2 * s + h][cl][0];
      s16x8 a1 = *(const s16x8*)&cst[buf][16 + 2 * s + h][cl][0];
      acc = __builtin_amdgcn_mfma_f32_32x32x16_bf16(a0, bh[s], acc, 0, 0, 0);
      acc = __builtin_amdgcn_mfma_f32_32x32x16_bf16(a0, bl[s], acc, 0, 0, 0);
      acc = __builtin_amdgcn_mfma_f32_32x32x16_bf16(a1, bh[s], acc, 0, 0, 0);
    }
    float4 c0 = *(const float4*)&cn_s[buf][h4];
    float4 c1 = *(const float4*)&cn_s[buf][8 + h4];
    float4 c2 = *(const float4*)&cn_s[buf][16 + h4];
    float4 c3 = *(const float4*)&cn_s[buf][24 + h4];
    const float cw[16] = {c0.x, c0.y, c0.z, c0.w, c1.x, c1.y, c1.z, c1.w,
                          c2.x, c2.y, c2.z, c2.w, c3.x, c3.y, c3.z, c3.w};
    const int ib = t * 32 + h4;
#pragma unroll
    for (int r = 0; r < 16; ++r) {
      const int idx = ib + (r & 3) + 8 * (r >> 2);
      float s = fmaf(-2.0f, acc[r], cw[r]);
      if (s <= Tc) {
        ++cnt;
        int e = (int)((Tc - s) * EQ);
        e = e > 0xFFFFF ? 0xFFFFF : e;
        unsigned key = ((unsigned)e << 12) | (unsigned)(4095 - idx);
        if (key > lA[11]) INS12U(lA, key);
      }
    }
    if (t < 127) {
      *(uint4*)&cst[buf ^ 1][su][sc][0] = st0;
      *(uint4*)&cst[buf ^ 1][16 + su][sc][0] = st1;
      if (tid < 32) cn_s[buf ^ 1][tid] = cnreg;
    }
    __syncthreads();
    buf ^= 1;
  }

  // ---- dump register lists into (now dead) cst LDS: dmp[256][2][12] u32
  unsigned* dmp = (unsigned*)&cst[0][0][0][0];   // 24.6 KB of 32.8 KB
#pragma unroll
  for (int j = 0; j < 12; ++j) dmp[((size_t)ql * 2 + h) * 12 + j] = lA[j];
  cnt2[ql][h] = (unsigned short)(cnt > 65535 ? 65535 : cnt);
  __syncthreads();

  // ---- certify tail: thread t<256 merges/certifies query t
  if (tid < QPB) {
    const int mq = tid;
    const int qg = qblk * QPB + mq;
    const int gq = z * 4096 + qg;
    const int c0 = cnt2[mq][0], c1 = cnt2[mq][1];
    const int k0 = c0 > 12 ? 12 : c0, k1 = c1 > 12 ? 12 : c1;
    const int m_true = c0 + c1;
    const unsigned* pa = &dmp[((size_t)mq * 2 + 0) * 12];
    const unsigned* pb = &dmp[((size_t)mq * 2 + 1) * 12];
    unsigned mg[10];
    int i = 0, j = 0;
#pragma unroll
    for (int s = 0; s < 10; ++s) {
      unsigned av = (i < k0) ? pa[i] : 0u;
      unsigned bv = (j < k1) ? pb[j] : 0u;
      bool ta = av >= bv;
      mg[s] = ta ? av : bv;
      if (ta) ++i; else ++j;
    }
    const unsigned e8 = mg[8] >> 12, e9 = mg[9] >> 12;
    const bool cov = (m_true >= 9) && (e8 >= GQCOV);
    const bool ok = cov && (m_true == 9 || (e8 - e9) >= GQGAP);
    const int row = (combo <= 1) ? qg : (N1 + qg);
    const int slot = (combo == 0 || combo == 2) ? 0 : 9;
    const int ioff = (combo == 1 || combo == 2) ? N1 : 0;
    int* dst = nbr + ((size_t)b * NT + row) * NBRS + slot;
    if (ok) {
#pragma unroll
      for (int s = 0; s < 9; ++s)
        dst[s] = (int)(4095u - (mg[s] & 0xFFFu)) + ioff;
    } else if (!cov) {
      int idx = atomicAdd(&cntg[1], 1);
      listB[idx] = (unsigned)gq;
    } else {
      int idx = atomicAdd(&cntg[0], 1);
      listA[idx] = ((unsigned)(k0 + k1) << 16) | (unsigned)gq;
      unsigned short* fp = fbl + (size_t)gq * 24;
      int p = 0;
      for (int t2 = 0; t2 < k0; ++t2) fp[p++] = (unsigned short)(4095u - (pa[t2] & 0xFFFu));
      for (int t2 = 0; t2 < k1; ++t2) fp[p++] = (unsigned short)(4095u - (pb[t2] & 0xFFFu));
    }
  }
}

// ------- rerank_sl: grid-stride over compacted shortlist queries (wave each)
__global__ __launch_bounds__(256) void rerank_sl_k(const float* __restrict__ xy,
                                                   const float* __restrict__ norms,
                                                   const unsigned short* __restrict__ fbl,
                                                   const unsigned* __restrict__ listA,
                                                   const int* __restrict__ cntg,
                                                   int* __restrict__ nbr) {
  const int lane = threadIdx.x & 63;
  const int wv = threadIdx.x >> 6;
  const int nA = cntg[0];
  for (int i = blockIdx.x * 4 + wv; i < nA; i += gridDim.x * 4) {
    const unsigned ent = listA[i];
    const int gq = (int)(ent & 0xffffu);
    const int m = (int)(ent >> 16);
    const int z = gq >> 12, q = gq & 4095;
    const int b = z >> 2, combo = z & 3;
    const int qoff = (combo <= 1) ? 0 : N1;
    const int coff = (combo == 0 || combo == 3) ? 0 : N1;
    const size_t cq = (size_t)b * NT + coff;
    const int row = (combo <= 1) ? q : (N1 + q);
    const int slot = (combo == 0 || combo == 2) ? 0 : 9;
    const int ioff = (combo == 1 || combo == 2) ? N1 : 0;
    int* dst = nbr + ((size_t)b * NT + row) * NBRS + slot;
    const float* qrow = xy + ((size_t)b * NT + qoff + q) * CH;

    int ci = 0; float de = FLT_MAX;
    if (lane < m) {
      ci = (int)fbl[(size_t)gq * 24 + lane];
      const float* crow = xy + (cq + ci) * CH;
      const float cnv = norms[cq + ci];
      float a0 = 0.f, a1 = 0.f, a2 = 0.f, a3 = 0.f;
#pragma unroll
      for (int k = 0; k < 32; ++k) {
        float4 qv = *(const float4*)(qrow + k * 4);
        float4 cv2 = *(const float4*)(crow + k * 4);
        a0 = fmaf(qv.x, cv2.x, a0); a1 = fmaf(qv.y, cv2.y, a1);
        a2 = fmaf(qv.z, cv2.z, a2); a3 = fmaf(qv.w, cv2.w, a3);
      }
      de = cnv - 2.0f * ((a0 + a1) + (a2 + a3));
    }
    unsigned long long key = ((unsigned long long)mapf(de) << 32) | (unsigned)ci;
    if (lane >= m) key = ~0ull;
    int xr = 0;
#pragma unroll 1
    for (int k = 0; k < m; ++k) {
      unsigned long long kk = __shfl(key, k);
      xr += (kk < key) ? 1 : 0;
    }
    if (lane < m && xr < 9) dst[xr] = ci + ioff;
  }
}

// ------- rerank_fs: grid-stride over full-scan queries (one BLOCK each)
__global__ __launch_bounds__(256) void rerank_fs_k(const float* __restrict__ xy,
                                                   const float* __restrict__ norms,
                                                   const unsigned* __restrict__ listB,
                                                   const int* __restrict__ cntg,
                                                   int* __restrict__ nbr) {
  __shared__ unsigned long long ms[4][576];
  __shared__ unsigned long long wk[36];
  const int tid = threadIdx.x;
  const int lane = tid & 63, wv = tid >> 6;
  const int nB = cntg[1];
  for (int i = blockIdx.x; i < nB; i += gridDim.x) {
    const int gq = (int)listB[i];
    const int z = gq >> 12, q = gq & 4095;
    const int b = z >> 2, combo = z & 3;
    const int qoff = (combo <= 1) ? 0 : N1;
    const int coff = (combo == 0 || combo == 3) ? 0 : N1;
    const size_t cq = (size_t)b * NT + coff;
    const int row = (combo <= 1) ? q : (N1 + q);
    const int slot = (combo == 0 || combo == 2) ? 0 : 9;
    const int ioff = (combo == 1 || combo == 2) ? N1 : 0;
    int* dst = nbr + ((size_t)b * NT + row) * NBRS + slot;
    const float* qrow = xy + ((size_t)b * NT + qoff + q) * CH;

    unsigned long long bl9[9];
#pragma unroll
    for (int j = 0; j < 9; ++j) bl9[j] = ~0ull;
    for (int it = 0; it < 16; ++it) {
      const int cc = (it * 4 + wv) * 64 + lane;
      const float* crow = xy + (cq + cc) * CH;
      float a0 = 0.f, a1 = 0.f, a2 = 0.f, a3 = 0.f;
#pragma unroll
      for (int k = 0; k < 32; ++k) {
        float4 qv = *(const float4*)(qrow + k * 4);
        float4 cv2 = *(const float4*)(crow + k * 4);
        a0 = fmaf(qv.x, cv2.x, a0); a1 = fmaf(qv.y, cv2.y, a1);
        a2 = fmaf(qv.z, cv2.z, a2); a3 = fmaf(qv.w, cv2.w, a3);
      }
      float d2v = norms[cq + cc] - 2.0f * ((a0 + a1) + (a2 + a3));
      unsigned long long key = ((unsigned long long)mapf(d2v) << 32) | (unsigned)cc;
      if (key < bl9[8]) {
#pragma unroll
        for (int jj = 0; jj < 9; ++jj) {
          bool sw = key < bl9[jj];
          unsigned long long tv = bl9[jj];
          bl9[jj] = sw ? key : tv;
          key = sw ? tv : key;
        }
      }
    }
#pragma unroll
    for (int s = 0; s < 9; ++s) ms[wv][lane * 9 + s] = bl9[s];
    int ptr = 0;
    for (int s = 0; s < 9; ++s) {
      unsigned long long hd = ms[wv][lane * 9 + ptr];
      unsigned long long mn = hd;
#pragma unroll
      for (int off = 1; off < 64; off <<= 1) {
        unsigned long long ot = __shfl_xor(mn, off);
        mn = (ot < mn) ? ot : mn;
      }
      unsigned long long wm = __ballot(hd == mn);
      int wl = __ffsll(wm) - 1;
      if (lane == wl) ptr++;
      if (lane == 0) wk[wv * 9 + s] = mn;
    }
    __syncthreads();
    if (wv == 0) {
      unsigned long long key = (lane < 36) ? wk[lane] : ~0ull;
      int xr = 0;
#pragma unroll 1
      for (int k = 0; k < 36; ++k) {
        unsigned long long kk = __shfl(key, k);
        xr += (kk < key) ? 1 : 0;
      }
      if (lane < 36 && xr < 9) dst[xr] = (int)(unsigned)(key & 0xffffffffull) + ioff;
    }
    __syncthreads();
  }
}

// ------------------------------------------- mrconv: gather+max+linear+BN+gelu
__global__ __launch_bounds__(256) void mrconv_k(const float* __restrict__ in,
                                                const int* __restrict__ nbr,
                                                const float* __restrict__ Wt,
                                                const float* __restrict__ bias,
                                                const float* __restrict__ gam,
                                                const float* __restrict__ bet,
                                                const float* __restrict__ mean,
                                                const float* __restrict__ var,
                                                float* __restrict__ out) {
  __shared__ float h[32][260];
  const int tid = threadIdx.x;
  const int pt0 = blockIdx.x * 32;
  {
    const int w = tid >> 6, lane = tid & 63;
    for (int pp = 0; pp < 8; ++pp) {
      const int p = w * 8 + pp;
      const int n = pt0 + p;
      const int b = n >> 13;
      const float* frow = in + (size_t)n * CH;
      float2 f2 = *(const float2*)(frow + lane * 2);
      float mx = -FLT_MAX, my = -FLT_MAX;
      const int* nb = nbr + (size_t)n * NBRS;
      for (int j = 0; j < NBRS; ++j) {
        int idx = nb[j];
        const float* vrow = in + ((size_t)b * NT + idx) * CH;
        float2 v2 = *(const float2*)(vrow + lane * 2);
        mx = fmaxf(mx, v2.x - f2.x);
        my = fmaxf(my, v2.y - f2.y);
      }
      h[p][lane * 4 + 0] = f2.x; h[p][lane * 4 + 1] = mx;
      h[p][lane * 4 + 2] = f2.y; h[p][lane * 4 + 3] = my;
    }
  }
  __syncthreads();
  const int o = tid & 127, gg = tid >> 7;
  float acc[16];
#pragma unroll
  for (int p = 0; p < 16; ++p) acc[p] = 0.f;
  for (int k = 0; k < 256; k += 4) {
    float w0 = Wt[(k + 0) * CH + o], w1 = Wt[(k + 1) * CH + o];
    float w2 = Wt[(k + 2) * CH + o], w3 = Wt[(k + 3) * CH + o];
#pragma unroll
    for (int p = 0; p < 16; ++p) {
      float4 hv = *(const float4*)&h[gg * 16 + p][k];
      acc[p] = fmaf(hv.x, w0, acc[p]);
      acc[p] = fmaf(hv.y, w1, acc[p]);
      acc[p] = fmaf(hv.z, w2, acc[p]);
      acc[p] = fmaf(hv.w, w3, acc[p]);
    }
  }
  const float sc = gam[o] / sqrtf(var[o] + 1e-5f);
  const float bs = bias[o], mo = mean[o], be = bet[o];
#pragma unroll
  for (int p = 0; p < 16; ++p) {
    const int n = pt0 + gg * 16 + p;
    float hv = acc[p] + bs;
    float bn = (hv - mo) * sc + be;
    float gl = 0.5f * bn * (1.0f + erff(bn * 0.70710678118654752f));
    out[(size_t)n * CH + o] = gl + h[gg * 16 + p][2 * o];
  }
}

// -------------------------------------------------------- fc: linear+BN+res
__global__ __launch_bounds__(256) void fc_k(const float* __restrict__ in,
                                            const float* __restrict__ Wt,
                                            const float* __restrict__ bias,
                                            const float* __restrict__ gam,
                                            const float* __restrict__ bet,
                                            const float* __restrict__ mean,
                                            const float* __restrict__ var,
                                            const float* __restrict__ xres,
                                            const float* __restrict__ yres,
                                            float* __restrict__ out) {
  __shared__ float s[32][132];
  const int tid = threadIdx.x;
  const int pt0 = blockIdx.x * 32;
  {
    const int w = tid >> 6, lane = tid & 63;
    for (int pp = 0; pp < 8; ++pp) {
      const int p = w * 8 + pp, n = pt0 + p;
      float2 v = *(const float2*)(in + (size_t)n * CH + lane * 2);
      s[p][lane * 2] = v.x; s[p][lane * 2 + 1] = v.y;
    }
  }
  __syncthreads();
  const int o = tid & 127, gg = tid >> 7;
  float acc[16];
#pragma unroll
  for (int p = 0; p < 16; ++p) acc[p] = 0.f;
  for (int k = 0; k < 128; k += 4) {
    float w0 = Wt[(k + 0) * CH + o], w1 = Wt[(k + 1) * CH + o];
    float w2 = Wt[(k + 2) * CH + o], w3 = Wt[(k + 3) * CH + o];
#pragma unroll
    for (int p = 0; p < 16; ++p) {
      float4 hv = *(const float4*)&s[gg * 16 + p][k];
      acc[p] = fmaf(hv.x, w0, fmaf(hv.y, w1, fmaf(hv.z, w2, fmaf(hv.w, w3, acc[p]))));
    }
  }
  const float sc = gam[o] / sqrtf(var[o] + 1e-5f);
  const float bs = bias[o], mo = mean[o], be = bet[o];
#pragma unroll
  for (int p = 0; p < 16; ++p) {
    const int n = pt0 + gg * 16 + p;
    const int b = n >> 13, row = n & 8191;
    float bn = (acc[p] + bs - mo) * sc + be;
    float res = (row < N1) ? xres[((size_t)b * N1 + row) * CH + o]
                           : yres[((size_t)b * N1 + row - N1) * CH + o];
    out[(size_t)n * CH + o] = bn + res;
  }
}

// ----------------------------------------------- ffn: 128->512->128 fused
__global__ __launch_bounds__(256) void ffn_k(const float* __restrict__ u,
                                             const float* __restrict__ W1t,
                                             const float* __restrict__ b1,
                                             const float* __restrict__ g1,
                                             const float* __restrict__ be1,
                                             const float* __restrict__ m1,
                                             const float* __restrict__ v1,
                                             const float* __restrict__ W2t,
                                             const float* __restrict__ b2,
                                             const float* __restrict__ g2,
                                             const float* __restrict__ be2,
                                             const float* __restrict__ m2,
                                             const float* __restrict__ v2,
                                             const float* __restrict__ xmask,
                                             const float* __restrict__ ymask,
                                             float* __restrict__ outbuf) {
  __shared__ float su[16][132];
  __shared__ float h1[16][516];
  const int tid = threadIdx.x;
  const int pt0 = blockIdx.x * 16;
  {
    const int w = tid >> 6, lane = tid & 63;
    for (int pp = 0; pp < 4; ++pp) {
      const int p = w * 4 + pp, n = pt0 + p;
      float2 v = *(const float2*)(u + (size_t)n * CH + lane * 2);
      su[p][lane * 2] = v.x; su[p][lane * 2 + 1] = v.y;
    }
  }
  __syncthreads();
  {
    const int o2 = tid;
    float a1[16], a2[16];
#pragma unroll
    for (int p = 0; p < 16; ++p) { a1[p] = 0.f; a2[p] = 0.f; }
    for (int k = 0; k < 128; k += 2) {
      float wA0 = W1t[(k + 0) * 512 + o2], wB0 = W1t[(k + 0) * 512 + o2 + 256];
      float wA1 = W1t[(k + 1) * 512 + o2], wB1 = W1t[(k + 1) * 512 + o2 + 256];
#pragma unroll
      for (int p = 0; p < 16; ++p) {
        float2 uv = *(const float2*)&su[p][k];
        a1[p] = fmaf(uv.x, wA0, fmaf(uv.y, wA1, a1[p]));
        a2[p] = fmaf(uv.x, wB0, fmaf(uv.y, wB1, a2[p]));
      }
    }
    float scA = g1[o2] / sqrtf(v1[o2] + 1e-5f);
    float scB = g1[o2 + 256] / sqrtf(v1[o2 + 256] + 1e-5f);
    float bsA = b1[o2], moA = m1[o2], beA = be1[o2];
    float bsB = b1[o2 + 256], moB = m1[o2 + 256], beB = be1[o2 + 256];
#pragma unroll
    for (int p = 0; p < 16; ++p) {
      float hA = (a1[p] + bsA - moA) * scA + beA;
      float hB = (a2[p] + bsB - moB) * scB + beB;
      h1[p][o2] = 0.5f * hA * (1.0f + erff(hA * 0.70710678118654752f));
      h1[p][o2 + 256] = 0.5f * hB * (1.0f + erff(hB * 0.70710678118654752f));
    }
  }
  __syncthreads();
  const int o = tid & 127, gg = tid >> 7;
  float acc[8];
#pragma unroll
  for (int p = 0; p < 8; ++p) acc[p] = 0.f;
  for (int k = 0; k < 512; k += 4) {
    float w0 = W2t[(k + 0) * CH + o], w1 = W2t[(k + 1) * CH + o];
    float w2 = W2t[(k + 2) * CH + o], w3 = W2t[(k + 3) * CH + o];
#pragma unroll
    for (int p = 0; p < 8; ++p) {
      float4 hv = *(const float4*)&h1[gg * 8 + p][k];
      acc[p] = fmaf(hv.x, w0, fmaf(hv.y, w1, fmaf(hv.z, w2, fmaf(hv.w, w3, acc[p]))));
    }
  }
  const float sc = g2[o] / sqrtf(v2[o] + 1e-5f);
  const float bs = b2[o], mo = m2[o], be = be2[o];
#pragma unroll
  for (int p = 0; p < 8; ++p) {
    const int n = pt0 + gg * 8 + p;
    const int b = n >> 13, row = n & 8191;
    float bn = (acc[p] + bs - mo) * sc + be;
    float gl = 0.5f * bn * (1.0f + erff(bn * 0.70710678118654752f));
    float res = su[gg * 8 + p][o];
    float msk; size_t oidx;
    if (row < N1) {
      msk = xmask[(size_t)b * N1 + row];
      oidx = ((size_t)b * N1 + row) * CH + o;
    } else {
      msk = ymask[(size_t)b * N1 + row - N1];
      oidx = (size_t)BB * N1 * CH + ((size_t)b * N1 + row - N1) * CH + o;
    }
    outbuf[oidx] = (gl + res) * msk;
  }
}

// ---------------------------------------------------------------------------
extern "C" void kernel_launch(void* const* d_in, const int* in_sizes, int n_in,
                              void* d_out, int out_size, void* d_ws, size_t ws_size,
                              hipStream_t stream) {
  const float* x  = (const float*)d_in[0];
  const float* y  = (const float*)d_in[1];
  const float* xm = (const float*)d_in[2];
  const float* ym = (const float*)d_in[3];
  const float* mr0W = (const float*)d_in[4];
  const float* mr1W = (const float*)d_in[10];
  const float* fcW  = (const float*)d_in[16];
  const float* f1W  = (const float*)d_in[22];
  const float* f2W  = (const float*)d_in[28];

  char* ws = (char*)d_ws;
  float*          xyA   = (float*)(ws + 0);                  // 16.78 MB
  unsigned short* cbt   = (unsigned short*)(ws + 16777216);  // 16.78 MB (dead after knn8)
  float*          xyB   = (float*)(ws + 16777216);           // alias over cbt
  float*          norms = (float*)(ws + 33554432);           // 131,072
  int*            cntg  = (int*)(ws + 33685504);             // 4,096
  unsigned*       listA = (unsigned*)(ws + 33689600);        // 262,144
  unsigned*       listB = (unsigned*)(ws + 33951744);        // 262,144
  unsigned short* fbl   = (unsigned short*)(ws + 34213888);  // 3.15 MB (24 u16/query)
  int*            nbr   = (int*)(ws + 37748736);             // 2,359,296
  float*          mr0t  = (float*)(ws + 40108032);           // 131,072
  float*          mr1t  = (float*)(ws + 40239104);           // 131,072
  float*          fct   = (float*)(ws + 40370176);           // 65,536
  float*          f1t   = (float*)(ws + 40435712);           // 262,144
  float*          f2t   = (float*)(ws + 40697856);           // 262,144 (end 40.96 MB)

  hipMemsetAsync(cntg, 0, 8, stream);

  transpose_k<<<(128 * 256 + 255) / 256, 256, 0, stream>>>(mr0W, mr0t, 128, 256);
  transpose_k<<<(128 * 256 + 255) / 256, 256, 0, stream>>>(mr1W, mr1t, 128, 256);
  transpose_k<<<(128 * 128 + 255) / 256, 256, 0, stream>>>(fcW, fct, 128, 128);
  transpose_k<<<(512 * 128 + 255) / 256, 256, 0, stream>>>(f1W, f1t, 512, 128);
  transpose_k<<<(128 * 512 + 255) / 256, 256, 0, stream>>>(f2W, f2t, 128, 512);

  norms_concat_k<<<8192, 256, 0, stream>>>(x, y, xyA, norms);
  cbt_k<<<2048, 256, 0, stream>>>(xyA, cbt);
  knn8_k<<<dim3(16, 16), 512, 0, stream>>>(cbt, norms, nbr, cntg, listA, listB, fbl);
  rerank_sl_k<<<256, 256, 0, stream>>>(xyA, norms, fbl, listA, cntg, nbr);
  rerank_fs_k<<<256, 256, 0, stream>>>(xyA, norms, listB, cntg, nbr);

  mrconv_k<<<1024, 256, 0, stream>>>(xyA, nbr, mr0t,
      (const float*)d_in[5], (const float*)d_in[6], (const float*)d_in[7],
      (const float*)d_in[8], (const float*)d_in[9], xyB);
  mrconv_k<<<1024, 256, 0, stream>>>(xyB, nbr, mr1t,
      (const float*)d_in[11], (const float*)d_in[12], (const float*)d_in[13],
      (const float*)d_in[14], (const float*)d_in[15], xyA);

  fc_k<<<1024, 256, 0, stream>>>(xyA, fct,
      (const float*)d_in[17], (const float*)d_in[18], (const float*)d_in[19],
      (const float*)d_in[20], (const float*)d_in[21], x, y, xyB);

  ffn_k<<<2048, 256, 0, stream>>>(xyB,
      f1t, (const float*)d_in[23], (const float*)d_in[24], (const float*)d_in[25],
      (const float*)d_in[26], (const float*)d_in[27],
      f2t, (const float*)d_in[29], (const float*)d_in[30], (const float*)d_in[31],
      (const float*)d_in[32], (const float*)d_in[33],
      xm, ym, (float*)d_out);
}

// Round 13
// 705.453 us; speedup vs baseline: 1.0111x; 1.0111x over previous
//
#include <hip/hip_runtime.h>
#include <hip/hip_bf16.h>
#include <float.h>
#include <math.h>

#define BB 4
#define N1 4096
#define NT 8192
#define CH 128
#define NBRS 18
#define ZSEL 2.35f
#define EQ 4096.0f     // e-quantum: 1/4096 score units (20-bit field)
#define GQGAP 6        // certify gap (quanta)
#define GQCOV 4        // coverage margin (quanta)
#define KPP 8          // kept entries per (query,h,half) partition-quarter

typedef __attribute__((ext_vector_type(8))) short s16x8;
typedef __attribute__((ext_vector_type(16))) float f32x16;

__device__ inline unsigned short f2bf(float v) {
  unsigned u = __float_as_uint(v);
  unsigned r = (u + 0x7FFFu + ((u >> 16) & 1u)) >> 16;
  return (unsigned short)r;
}

__device__ inline unsigned mapf(float f) {
  unsigned u = __float_as_uint(f);
  return (u & 0x80000000u) ? ~u : (u | 0x80000000u);
}

#define INS8U(l, key0)                          \
  {                                             \
    unsigned nk = key0;                         \
    _Pragma("unroll")                           \
    for (int j = 0; j < KPP; ++j) {             \
      bool sw = nk > l[j];                      \
      unsigned tv = l[j];                       \
      l[j] = sw ? nk : tv;                      \
      nk = sw ? tv : nk;                        \
    }                                           \
  }

// ---------------------------------------------------------------- transpose
__global__ __launch_bounds__(256) void transpose_k(const float* __restrict__ in,
                                                   float* __restrict__ out,
                                                   int rows, int cols) {
  int t = blockIdx.x * 256 + threadIdx.x;
  if (t < rows * cols) {
    int r = t / cols, c = t % cols;
    out[c * rows + r] = in[t];
  }
}

// ------------------------------------------------- concat x,y + squared norms
__global__ __launch_bounds__(256) void norms_concat_k(const float* __restrict__ x,
                                                      const float* __restrict__ y,
                                                      float* __restrict__ xy,
                                                      float* __restrict__ norms) {
  int w = (blockIdx.x * 256 + threadIdx.x) >> 6;  // global point id, 0..32767
  int lane = threadIdx.x & 63;
  int b = w >> 13, row = w & 8191;
  const float* src = (row < N1) ? (x + ((size_t)b * N1 + row) * CH)
                                : (y + ((size_t)b * N1 + (row - N1)) * CH);
  float2 v = *(const float2*)(src + lane * 2);
  *(float2*)(xy + (size_t)w * CH + lane * 2) = v;
  float s = v.x * v.x + v.y * v.y;
  for (int off = 32; off > 0; off >>= 1) s += __shfl_down(s, off);
  if (lane == 0) norms[w] = s;
}

// ---------------------------------------- build split-bf16 k-major candidate buf
__global__ __launch_bounds__(256) void cbt_k(const float* __restrict__ xy,
                                             unsigned short* __restrict__ cbt) {
  int t = blockIdx.x * 256 + threadIdx.x;  // 32768*16
  int u = t >> 15, p = t & 32767;
  const float* src = xy + (size_t)p * CH + u * 8;
  unsigned hw[4], lw[4];
#pragma unroll
  for (int j = 0; j < 4; ++j) {
    float v0 = src[2 * j], v1 = src[2 * j + 1];
    unsigned short h0 = f2bf(v0), h1 = f2bf(v1);
    float r0 = v0 - __uint_as_float((unsigned)h0 << 16);
    float r1 = v1 - __uint_as_float((unsigned)h1 << 16);
    unsigned short l0 = f2bf(r0), l1 = f2bf(r1);
    hw[j] = (unsigned)h0 | ((unsigned)h1 << 16);
    lw[j] = (unsigned)l0 | ((unsigned)l1 << 16);
  }
  *(uint4*)&cbt[((size_t)u * 32768 + p) * 8] = make_uint4(hw[0], hw[1], hw[2], hw[3]);
  *(uint4*)&cbt[((size_t)(u + 16) * 32768 + p) * 8] = make_uint4(lw[0], lw[1], lw[2], lw[3]);
}

// ---------- MFMA knn: per-lane 8-deep register lists; `half` is a launch arg
// so each launch is ~half the work and shorter than any hidden heavy kernel
// (diagnostic: forces unknown >135us dispatches into the top-5 table).
// grid (32 qblk, 16 z) x 2 launches, 256 thr = 4 waves.
__global__ __launch_bounds__(256) void knn6_k(const unsigned short* __restrict__ cbt,
                                              const float* __restrict__ norms,
                                              unsigned* __restrict__ pl,
                                              unsigned char* __restrict__ cnts,
                                              int half) {
  __shared__ unsigned short __align__(16) cst[2][32][32][8];  // 32.8 KB
  __shared__ float cn_s[2][32];
  const int tid = threadIdx.x;
  const int qblk = blockIdx.x, z = blockIdx.y;
  const int b = z >> 2, combo = z & 3;
  const int qoff = (combo <= 1) ? 0 : N1;
  const int coff = (combo == 0 || combo == 3) ? 0 : N1;
  const int w = tid >> 6;
  const int cl = tid & 31;
  const int h = (tid >> 5) & 1;
  const int h4 = 4 * h;
  const int ql = w * 32 + cl;          // query-local 0..127
  const int q = qblk * 128 + ql;
  const size_t qp = (size_t)b * NT + qoff + q;
  const size_t cb0 = (size_t)b * NT + coff + half * 2048;

  const s16x8* cv = (const s16x8*)cbt;
  s16x8 bh[8], bl[8];
#pragma unroll
  for (int s = 0; s < 8; ++s) {
    bh[s] = cv[(size_t)(2 * s + h) * 32768 + qp];
    bl[s] = cv[(size_t)(16 + 2 * s + h) * 32768 + qp];
  }

  const float nq = norms[qp];
  const float Tc = 128.f - ZSEL * sqrtf(256.f + 4.f * nq);
  int cnt = 0;
  unsigned lA[KPP];
#pragma unroll
  for (int j = 0; j < KPP; ++j) lA[j] = 0u;

  const int su = tid >> 5, sc = tid & 31;
  const char* p0 = (const char*)&cbt[((size_t)(su) * 32768 + cb0 + sc) * 8];
  const char* p1 = (const char*)&cbt[((size_t)(8 + su) * 32768 + cb0 + sc) * 8];
  const char* p2 = (const char*)&cbt[((size_t)(16 + su) * 32768 + cb0 + sc) * 8];
  const char* p3 = (const char*)&cbt[((size_t)(24 + su) * 32768 + cb0 + sc) * 8];
  const float* pn = norms + cb0 + tid;

  uint4 st[4]; float cnreg = 0.f;
  st[0] = *(const uint4*)p0; p0 += 512;
  st[1] = *(const uint4*)p1; p1 += 512;
  st[2] = *(const uint4*)p2; p2 += 512;
  st[3] = *(const uint4*)p3; p3 += 512;
  if (tid < 32) { cnreg = *pn; pn += 32; }
  *(uint4*)&cst[0][su][sc][0] = st[0];
  *(uint4*)&cst[0][8 + su][sc][0] = st[1];
  *(uint4*)&cst[0][16 + su][sc][0] = st[2];
  *(uint4*)&cst[0][24 + su][sc][0] = st[3];
  if (tid < 32) cn_s[0][tid] = cnreg;
  __syncthreads();

  int buf = 0;
  for (int t = 0; t < 64; ++t) {
    if (t < 63) {
      st[0] = *(const uint4*)p0; p0 += 512;
      st[1] = *(const uint4*)p1; p1 += 512;
      st[2] = *(const uint4*)p2; p2 += 512;
      st[3] = *(const uint4*)p3; p3 += 512;
      if (tid < 32) { cnreg = *pn; pn += 32; }
    }
    f32x16 acc = {0.f,0.f,0.f,0.f,0.f,0.f,0.f,0.f,0.f,0.f,0.f,0.f,0.f,0.f,0.f,0.f};
#pragma unroll
    for (int s = 0; s < 8; ++s) {
      s16x8 a0 = *(const s16x8*)&cst[buf][2 * s + h][cl][0];
      s16x8 a1 = *(const s16x8*)&cst[buf][16 + 2 * s + h][cl][0];
      acc = __builtin_amdgcn_mfma_f32_32x32x16_bf16(a0, bh[s], acc, 0, 0, 0);
      acc = __builtin_amdgcn_mfma_f32_32x32x16_bf16(a0, bl[s], acc, 0, 0, 0);
      acc = __builtin_amdgcn_mfma_f32_32x32x16_bf16(a1, bh[s], acc, 0, 0, 0);
    }
    float4 c0 = *(const float4*)&cn_s[buf][h4];
    float4 c1 = *(const float4*)&cn_s[buf][8 + h4];
    float4 c2 = *(const float4*)&cn_s[buf][16 + h4];
    float4 c3 = *(const float4*)&cn_s[buf][24 + h4];
    const float cw[16] = {c0.x, c0.y, c0.z, c0.w, c1.x, c1.y, c1.z, c1.w,
                          c2.x, c2.y, c2.z, c2.w, c3.x, c3.y, c3.z, c3.w};
    const int ib = half * 2048 + t * 32 + h4;
#pragma unroll
    for (int r = 0; r < 16; ++r) {
      const int idx = ib + (r & 3) + 8 * (r >> 2);
      float s = fmaf(-2.0f, acc[r], cw[r]);
      if (s <= Tc) {
        ++cnt;
        int e = (int)((Tc - s) * EQ);
        e = e > 0xFFFFF ? 0xFFFFF : e;
        unsigned key = ((unsigned)e << 12) | (unsigned)(4095 - idx);
        if (key > lA[KPP - 1]) INS8U(lA, key);
      }
    }
    if (t < 63) {
      *(uint4*)&cst[buf ^ 1][su][sc][0] = st[0];
      *(uint4*)&cst[buf ^ 1][8 + su][sc][0] = st[1];
      *(uint4*)&cst[buf ^ 1][16 + su][sc][0] = st[2];
      *(uint4*)&cst[buf ^ 1][24 + su][sc][0] = st[3];
      if (tid < 32) cn_s[buf ^ 1][tid] = cnreg;
    }
    __syncthreads();
    buf ^= 1;
  }

  const size_t lbase = (((size_t)(z * 4096 + q) * 2 + h) * 2 + half) * KPP;
#pragma unroll
  for (int j = 0; j < KPP; ++j) pl[lbase + j] = lA[j];
  cnts[((size_t)(z * 4096 + q) * 2 + h) * 2 + half] =
      (unsigned char)(cnt > 255 ? 255 : cnt);
}

// -------- merge_cert: one thread per query. 4-way merge of kept lists ->
// top-10, soundness guards, certify & write or compact to listA/listB.
__global__ __launch_bounds__(256) void merge_cert_k(const unsigned* __restrict__ pl,
                                                    const unsigned char* __restrict__ cnts,
                                                    int* __restrict__ nbr,
                                                    int* __restrict__ cntg,
                                                    unsigned* __restrict__ listA,
                                                    unsigned* __restrict__ listB) {
  const int gq = blockIdx.x * 256 + threadIdx.x;  // 0..65535
  const int z = gq >> 12, q = gq & 4095;
  const int b = z >> 2, combo = z & 3;
  const uchar4 cc = *(const uchar4*)&cnts[(size_t)gq * 4];
  const int c[4] = {cc.x, cc.y, cc.z, cc.w};
  int k[4];
#pragma unroll
  for (int i = 0; i < 4; ++i) k[i] = c[i] > KPP ? KPP : c[i];
  const int m_true = c[0] + c[1] + c[2] + c[3];
  const int m_kept = k[0] + k[1] + k[2] + k[3];

  unsigned arr[32];
  {
    const uint4* pb = (const uint4*)&pl[(size_t)gq * 32];
#pragma unroll
    for (int i = 0; i < 8; ++i) {
      uint4 v = pb[i];
      arr[i * 4 + 0] = v.x; arr[i * 4 + 1] = v.y;
      arr[i * 4 + 2] = v.z; arr[i * 4 + 3] = v.w;
    }
  }
#pragma unroll
  for (int i = 0; i < 4; ++i)
#pragma unroll
    for (int p = 0; p < KPP; ++p)
      if (p >= k[i]) arr[i * KPP + p] = 0u;

  unsigned mg[10];
  unsigned cur = 0u; bool first = true;
#pragma unroll
  for (int s = 0; s < 10; ++s) {
    unsigned mx = 0u;
#pragma unroll
    for (int j = 0; j < 32; ++j) {
      unsigned v = arr[j];
      v = (first || v < cur) ? v : 0u;
      mx = v > mx ? v : mx;
    }
    mg[s] = mx; cur = mx; first = false;
  }
  const unsigned e8 = mg[8] >> 12, e9 = mg[9] >> 12;
  bool incomplete = false;
#pragma unroll
  for (int i = 0; i < 4; ++i)
    if (c[i] > KPP && arr[i * KPP + KPP - 1] >= mg[9]) incomplete = true;

  const int row = (combo <= 1) ? q : (N1 + q);
  const int slot = (combo == 0 || combo == 2) ? 0 : 9;
  const int ioff = (combo == 1 || combo == 2) ? N1 : 0;
  int* dst = nbr + ((size_t)b * NT + row) * NBRS + slot;

  if (m_true < 9 || m_kept < 9 || incomplete || e8 < GQCOV) {
    int idx = atomicAdd(&cntg[1], 1);
    listB[idx] = (unsigned)gq;
  } else if (m_true == 9 || (e8 - e9) >= GQGAP) {
#pragma unroll
    for (int s = 0; s < 9; ++s)
      dst[s] = (int)(4095u - (mg[s] & 0xFFFu)) + ioff;
  } else {
    int idx = atomicAdd(&cntg[0], 1);
    listA[idx] = ((unsigned)m_kept << 16) | (unsigned)gq;
  }
}

// ------- rerank_sl: grid-stride over compacted shortlist queries (wave each)
__global__ __launch_bounds__(256) void rerank_sl_k(const float* __restrict__ xy,
                                                   const float* __restrict__ norms,
                                                   const unsigned* __restrict__ pl,
                                                   const unsigned char* __restrict__ cnts,
                                                   const unsigned* __restrict__ listA,
                                                   const int* __restrict__ cntg,
                                                   int* __restrict__ nbr) {
  const int lane = threadIdx.x & 63;
  const int wv = threadIdx.x >> 6;
  const int nA = cntg[0];
  for (int i = blockIdx.x * 4 + wv; i < nA; i += gridDim.x * 4) {
    const unsigned ent = listA[i];
    const int gq = (int)(ent & 0xffffu);
    const int m = (int)(ent >> 16);
    const int z = gq >> 12, q = gq & 4095;
    const int b = z >> 2, combo = z & 3;
    const int qoff = (combo <= 1) ? 0 : N1;
    const int coff = (combo == 0 || combo == 3) ? 0 : N1;
    const size_t cq = (size_t)b * NT + coff;
    const int row = (combo <= 1) ? q : (N1 + q);
    const int slot = (combo == 0 || combo == 2) ? 0 : 9;
    const int ioff = (combo == 1 || combo == 2) ? N1 : 0;
    int* dst = nbr + ((size_t)b * NT + row) * NBRS + slot;
    const float* qrow = xy + ((size_t)b * NT + qoff + q) * CH;

    const uchar4 cc = *(const uchar4*)&cnts[(size_t)gq * 4];
    const int k0 = cc.x > KPP ? KPP : cc.x, k1 = cc.y > KPP ? KPP : cc.y;
    const int k2 = cc.z > KPP ? KPP : cc.z;
    const int o1 = k0, o2 = k0 + k1, o3 = o2 + k2;

    int ci = 0; float de = FLT_MAX;
    if (lane < m) {
      const int li = (lane >= o1) + (lane >= o2) + (lane >= o3);
      const int pos = lane - (li == 0 ? 0 : li == 1 ? o1 : li == 2 ? o2 : o3);
      const unsigned key = pl[(size_t)gq * 32 + li * KPP + pos];
      ci = (int)(4095u - (key & 0xFFFu));
      const float* crow = xy + (cq + ci) * CH;
      const float cnv = norms[cq + ci];
      float a0 = 0.f, a1 = 0.f, a2 = 0.f, a3 = 0.f;
#pragma unroll
      for (int kk = 0; kk < 32; ++kk) {
        float4 qv = *(const float4*)(qrow + kk * 4);
        float4 cv2 = *(const float4*)(crow + kk * 4);
        a0 = fmaf(qv.x, cv2.x, a0); a1 = fmaf(qv.y, cv2.y, a1);
        a2 = fmaf(qv.z, cv2.z, a2); a3 = fmaf(qv.w, cv2.w, a3);
      }
      de = cnv - 2.0f * ((a0 + a1) + (a2 + a3));
    }
    unsigned long long key64 = ((unsigned long long)mapf(de) << 32) | (unsigned)ci;
    if (lane >= m) key64 = ~0ull;
    int xr = 0;
#pragma unroll 1
    for (int kk = 0; kk < m; ++kk) {
      unsigned long long kk2 = __shfl(key64, kk);
      xr += (kk2 < key64) ? 1 : 0;
    }
    if (lane < m && xr < 9) dst[xr] = ci + ioff;
  }
}

// ------- rerank_fs: grid-stride over full-scan queries (one BLOCK each)
__global__ __launch_bounds__(256) void rerank_fs_k(const float* __restrict__ xy,
                                                   const float* __restrict__ norms,
                                                   const unsigned* __restrict__ listB,
                                                   const int* __restrict__ cntg,
                                                   int* __restrict__ nbr) {
  __shared__ unsigned long long ms[4][576];
  __shared__ unsigned long long wk[36];
  const int tid = threadIdx.x;
  const int lane = tid & 63, wv = tid >> 6;
  const int nB = cntg[1];
  for (int i = blockIdx.x; i < nB; i += gridDim.x) {
    const int gq = (int)listB[i];
    const int z = gq >> 12, q = gq & 4095;
    const int b = z >> 2, combo = z & 3;
    const int qoff = (combo <= 1) ? 0 : N1;
    const int coff = (combo == 0 || combo == 3) ? 0 : N1;
    const size_t cq = (size_t)b * NT + coff;
    const int row = (combo <= 1) ? q : (N1 + q);
    const int slot = (combo == 0 || combo == 2) ? 0 : 9;
    const int ioff = (combo == 1 || combo == 2) ? N1 : 0;
    int* dst = nbr + ((size_t)b * NT + row) * NBRS + slot;
    const float* qrow = xy + ((size_t)b * NT + qoff + q) * CH;

    unsigned long long bl9[9];
#pragma unroll
    for (int j = 0; j < 9; ++j) bl9[j] = ~0ull;
    for (int it = 0; it < 16; ++it) {
      const int cc = (it * 4 + wv) * 64 + lane;
      const float* crow = xy + (cq + cc) * CH;
      float a0 = 0.f, a1 = 0.f, a2 = 0.f, a3 = 0.f;
#pragma unroll
      for (int kk = 0; kk < 32; ++kk) {
        float4 qv = *(const float4*)(qrow + kk * 4);
        float4 cv2 = *(const float4*)(crow + kk * 4);
        a0 = fmaf(qv.x, cv2.x, a0); a1 = fmaf(qv.y, cv2.y, a1);
        a2 = fmaf(qv.z, cv2.z, a2); a3 = fmaf(qv.w, cv2.w, a3);
      }
      float d2v = norms[cq + cc] - 2.0f * ((a0 + a1) + (a2 + a3));
      unsigned long long key = ((unsigned long long)mapf(d2v) << 32) | (unsigned)cc;
      if (key < bl9[8]) {
#pragma unroll
        for (int jj = 0; jj < 9; ++jj) {
          bool sw = key < bl9[jj];
          unsigned long long tv = bl9[jj];
          bl9[jj] = sw ? key : tv;
          key = sw ? tv : key;
        }
      }
    }
#pragma unroll
    for (int s = 0; s < 9; ++s) ms[wv][lane * 9 + s] = bl9[s];
    int ptr = 0;
    for (int s = 0; s < 9; ++s) {
      unsigned long long hd = ms[wv][lane * 9 + ptr];
      unsigned long long mn = hd;
#pragma unroll
      for (int off = 1; off < 64; off <<= 1) {
        unsigned long long ot = __shfl_xor(mn, off);
        mn = (ot < mn) ? ot : mn;
      }
      unsigned long long wm = __ballot(hd == mn);
      int wl = __ffsll(wm) - 1;
      if (lane == wl) ptr++;
      if (lane == 0) wk[wv * 9 + s] = mn;
    }
    __syncthreads();
    if (wv == 0) {
      unsigned long long key = (lane < 36) ? wk[lane] : ~0ull;
      int xr = 0;
#pragma unroll 1
      for (int kk = 0; kk < 36; ++kk) {
        unsigned long long kk2 = __shfl(key, kk);
        xr += (kk2 < key) ? 1 : 0;
      }
      if (lane < 36 && xr < 9) dst[xr] = (int)(unsigned)(key & 0xffffffffull) + ioff;
    }
    __syncthreads();
  }
}

// ------------------------------------------- mrconv: gather+max+linear+BN+gelu
__global__ __launch_bounds__(256) void mrconv_k(const float* __restrict__ in,
                                                const int* __restrict__ nbr,
                                                const float* __restrict__ Wt,
                                                const float* __restrict__ bias,
                                                const float* __restrict__ gam,
                                                const float* __restrict__ bet,
                                                const float* __restrict__ mean,
                                                const float* __restrict__ var,
                                                float* __restrict__ out) {
  __shared__ float h[32][260];
  const int tid = threadIdx.x;
  const int pt0 = blockIdx.x * 32;
  {
    const int w = tid >> 6, lane = tid & 63;
    for (int pp = 0; pp < 8; ++pp) {
      const int p = w * 8 + pp;
      const int n = pt0 + p;
      const int b = n >> 13;
      const float* frow = in + (size_t)n * CH;
      float2 f2 = *(const float2*)(frow + lane * 2);
      float mx = -FLT_MAX, my = -FLT_MAX;
      const int* nb = nbr + (size_t)n * NBRS;
      for (int j = 0; j < NBRS; ++j) {
        int idx = nb[j];
        const float* vrow = in + ((size_t)b * NT + idx) * CH;
        float2 v2 = *(const float2*)(vrow + lane * 2);
        mx = fmaxf(mx, v2.x - f2.x);
        my = fmaxf(my, v2.y - f2.y);
      }
      h[p][lane * 4 + 0] = f2.x; h[p][lane * 4 + 1] = mx;
      h[p][lane * 4 + 2] = f2.y; h[p][lane * 4 + 3] = my;
    }
  }
  __syncthreads();
  const int o = tid & 127, gg = tid >> 7;
  float acc[16];
#pragma unroll
  for (int p = 0; p < 16; ++p) acc[p] = 0.f;
  for (int k = 0; k < 256; k += 4) {
    float w0 = Wt[(k + 0) * CH + o], w1 = Wt[(k + 1) * CH + o];
    float w2 = Wt[(k + 2) * CH + o], w3 = Wt[(k + 3) * CH + o];
#pragma unroll
    for (int p = 0; p < 16; ++p) {
      float4 hv = *(const float4*)&h[gg * 16 + p][k];
      acc[p] = fmaf(hv.x, w0, acc[p]);
      acc[p] = fmaf(hv.y, w1, acc[p]);
      acc[p] = fmaf(hv.z, w2, acc[p]);
      acc[p] = fmaf(hv.w, w3, acc[p]);
    }
  }
  const float sc = gam[o] / sqrtf(var[o] + 1e-5f);
  const float bs = bias[o], mo = mean[o], be = bet[o];
#pragma unroll
  for (int p = 0; p < 16; ++p) {
    const int n = pt0 + gg * 16 + p;
    float hv = acc[p] + bs;
    float bn = (hv - mo) * sc + be;
    float gl = 0.5f * bn * (1.0f + erff(bn * 0.70710678118654752f));
    out[(size_t)n * CH + o] = gl + h[gg * 16 + p][2 * o];
  }
}

// -------------------------------------------------------- fc: linear+BN+res
__global__ __launch_bounds__(256) void fc_k(const float* __restrict__ in,
                                            const float* __restrict__ Wt,
                                            const float* __restrict__ bias,
                                            const float* __restrict__ gam,
                                            const float* __restrict__ bet,
                                            const float* __restrict__ mean,
                                            const float* __restrict__ var,
                                            const float* __restrict__ xres,
                                            const float* __restrict__ yres,
                                            float* __restrict__ out) {
  __shared__ float s[32][132];
  const int tid = threadIdx.x;
  const int pt0 = blockIdx.x * 32;
  {
    const int w = tid >> 6, lane = tid & 63;
    for (int pp = 0; pp < 8; ++pp) {
      const int p = w * 8 + pp, n = pt0 + p;
      float2 v = *(const float2*)(in + (size_t)n * CH + lane * 2);
      s[p][lane * 2] = v.x; s[p][lane * 2 + 1] = v.y;
    }
  }
  __syncthreads();
  const int o = tid & 127, gg = tid >> 7;
  float acc[16];
#pragma unroll
  for (int p = 0; p < 16; ++p) acc[p] = 0.f;
  for (int k = 0; k < 128; k += 4) {
    float w0 = Wt[(k + 0) * CH + o], w1 = Wt[(k + 1) * CH + o];
    float w2 = Wt[(k + 2) * CH + o], w3 = Wt[(k + 3) * CH + o];
#pragma unroll
    for (int p = 0; p < 16; ++p) {
      float4 hv = *(const float4*)&s[gg * 16 + p][k];
      acc[p] = fmaf(hv.x, w0, fmaf(hv.y, w1, fmaf(hv.z, w2, fmaf(hv.w, w3, acc[p]))));
    }
  }
  const float sc = gam[o] / sqrtf(var[o] + 1e-5f);
  const float bs = bias[o], mo = mean[o], be = bet[o];
#pragma unroll
  for (int p = 0; p < 16; ++p) {
    const int n = pt0 + gg * 16 + p;
    const int b = n >> 13, row = n & 8191;
    float bn = (acc[p] + bs - mo) * sc + be;
    float res = (row < N1) ? xres[((size_t)b * N1 + row) * CH + o]
                           : yres[((size_t)b * N1 + row - N1) * CH + o];
    out[(size_t)n * CH + o] = bn + res;
  }
}

// ----------------------------------------------- ffn: 128->512->128 fused
__global__ __launch_bounds__(256) void ffn_k(const float* __restrict__ u,
                                             const float* __restrict__ W1t,
                                             const float* __restrict__ b1,
                                             const float* __restrict__ g1,
                                             const float* __restrict__ be1,
                                             const float* __restrict__ m1,
                                             const float* __restrict__ v1,
                                             const float* __restrict__ W2t,
                                             const float* __restrict__ b2,
                                             const float* __restrict__ g2,
                                             const float* __restrict__ be2,
                                             const float* __restrict__ m2,
                                             const float* __restrict__ v2,
                                             const float* __restrict__ xmask,
                                             const float* __restrict__ ymask,
                                             float* __restrict__ outbuf) {
  __shared__ float su[16][132];
  __shared__ float h1[16][516];
  const int tid = threadIdx.x;
  const int pt0 = blockIdx.x * 16;
  {
    const int w = tid >> 6, lane = tid & 63;
    for (int pp = 0; pp < 4; ++pp) {
      const int p = w * 4 + pp, n = pt0 + p;
      float2 v = *(const float2*)(u + (size_t)n * CH + lane * 2);
      su[p][lane * 2] = v.x; su[p][lane * 2 + 1] = v.y;
    }
  }
  __syncthreads();
  {
    const int o2 = tid;
    float a1[16], a2[16];
#pragma unroll
    for (int p = 0; p < 16; ++p) { a1[p] = 0.f; a2[p] = 0.f; }
    for (int k = 0; k < 128; k += 2) {
      float wA0 = W1t[(k + 0) * 512 + o2], wB0 = W1t[(k + 0) * 512 + o2 + 256];
      float wA1 = W1t[(k + 1) * 512 + o2], wB1 = W1t[(k + 1) * 512 + o2 + 256];
#pragma unroll
      for (int p = 0; p < 16; ++p) {
        float2 uv = *(const float2*)&su[p][k];
        a1[p] = fmaf(uv.x, wA0, fmaf(uv.y, wA1, a1[p]));
        a2[p] = fmaf(uv.x, wB0, fmaf(uv.y, wB1, a2[p]));
      }
    }
    float scA = g1[o2] / sqrtf(v1[o2] + 1e-5f);
    float scB = g1[o2 + 256] / sqrtf(v1[o2 + 256] + 1e-5f);
    float bsA = b1[o2], moA = m1[o2], beA = be1[o2];
    float bsB = b1[o2 + 256], moB = m1[o2 + 256], beB = be1[o2 + 256];
#pragma unroll
    for (int p = 0; p < 16; ++p) {
      float hA = (a1[p] + bsA - moA) * scA + beA;
      float hB = (a2[p] + bsB - moB) * scB + beB;
      h1[p][o2] = 0.5f * hA * (1.0f + erff(hA * 0.70710678118654752f));
      h1[p][o2 + 256] = 0.5f * hB * (1.0f + erff(hB * 0.70710678118654752f));
    }
  }
  __syncthreads();
  const int o = tid & 127, gg = tid >> 7;
  float acc[8];
#pragma unroll
  for (int p = 0; p < 8; ++p) acc[p] = 0.f;
  for (int k = 0; k < 512; k += 4) {
    float w0 = W2t[(k + 0) * CH + o], w1 = W2t[(k + 1) * CH + o];
    float w2 = W2t[(k + 2) * CH + o], w3 = W2t[(k + 3) * CH + o];
#pragma unroll
    for (int p = 0; p < 8; ++p) {
      float4 hv = *(const float4*)&h1[gg * 8 + p][k];
      acc[p] = fmaf(hv.x, w0, fmaf(hv.y, w1, fmaf(hv.z, w2, fmaf(hv.w, w3, acc[p]))));
    }
  }
  const float sc = g2[o] / sqrtf(v2[o] + 1e-5f);
  const float bs = b2[o], mo = m2[o], be = be2[o];
#pragma unroll
  for (int p = 0; p < 8; ++p) {
    const int n = pt0 + gg * 8 + p;
    const int b = n >> 13, row = n & 8191;
    float bn = (acc[p] + bs - mo) * sc + be;
    float gl = 0.5f * bn * (1.0f + erff(bn * 0.70710678118654752f));
    float res = su[gg * 8 + p][o];
    float msk; size_t oidx;
    if (row < N1) {
      msk = xmask[(size_t)b * N1 + row];
      oidx = ((size_t)b * N1 + row) * CH + o;
    } else {
      msk = ymask[(size_t)b * N1 + row - N1];
      oidx = (size_t)BB * N1 * CH + ((size_t)b * N1 + row - N1) * CH + o;
    }
    outbuf[oidx] = (gl + res) * msk;
  }
}

// ---------------------------------------------------------------------------
extern "C" void kernel_launch(void* const* d_in, const int* in_sizes, int n_in,
                              void* d_out, int out_size, void* d_ws, size_t ws_size,
                              hipStream_t stream) {
  const float* x  = (const float*)d_in[0];
  const float* y  = (const float*)d_in[1];
  const float* xm = (const float*)d_in[2];
  const float* ym = (const float*)d_in[3];
  const float* mr0W = (const float*)d_in[4];
  const float* mr1W = (const float*)d_in[10];
  const float* fcW  = (const float*)d_in[16];
  const float* f1W  = (const float*)d_in[22];
  const float* f2W  = (const float*)d_in[28];

  char* ws = (char*)d_ws;
  float*          xyA   = (float*)(ws + 0);                  // 16.78 MB
  unsigned short* cbt   = (unsigned short*)(ws + 16777216);  // 16.78 MB (dead after knn6)
  float*          xyB   = (float*)(ws + 16777216);           // alias over cbt
  float*          norms = (float*)(ws + 33554432);           // 131,072
  int*            cntg  = (int*)(ws + 33685504);             // 4,096
  unsigned*       listA = (unsigned*)(ws + 33689600);        // 262,144
  unsigned*       listB = (unsigned*)(ws + 33951744);        // 262,144
  unsigned*       pl    = (unsigned*)(ws + 34213888);        // 8,388,608
  unsigned char*  cnts  = (unsigned char*)(ws + 42602496);   // 262,144
  int*            nbr   = (int*)(ws + 42864640);             // 2,359,296
  float*          mr0t  = (float*)(ws + 45223936);           // 131,072
  float*          mr1t  = (float*)(ws + 45355008);           // 131,072
  float*          fct   = (float*)(ws + 45486080);           // 65,536
  float*          f1t   = (float*)(ws + 45551616);           // 262,144
  float*          f2t   = (float*)(ws + 45813760);           // 262,144 (end 46,075,904)

  hipMemsetAsync(cntg, 0, 8, stream);

  transpose_k<<<(128 * 256 + 255) / 256, 256, 0, stream>>>(mr0W, mr0t, 128, 256);
  transpose_k<<<(128 * 256 + 255) / 256, 256, 0, stream>>>(mr1W, mr1t, 128, 256);
  transpose_k<<<(128 * 128 + 255) / 256, 256, 0, stream>>>(fcW, fct, 128, 128);
  transpose_k<<<(512 * 128 + 255) / 256, 256, 0, stream>>>(f1W, f1t, 512, 128);
  transpose_k<<<(128 * 512 + 255) / 256, 256, 0, stream>>>(f2W, f2t, 128, 512);

  norms_concat_k<<<8192, 256, 0, stream>>>(x, y, xyA, norms);
  cbt_k<<<2048, 256, 0, stream>>>(xyA, cbt);
  knn6_k<<<dim3(32, 16), 256, 0, stream>>>(cbt, norms, pl, cnts, 0);
  knn6_k<<<dim3(32, 16), 256, 0, stream>>>(cbt, norms, pl, cnts, 1);
  merge_cert_k<<<256, 256, 0, stream>>>(pl, cnts, nbr, cntg, listA, listB);
  rerank_sl_k<<<256, 256, 0, stream>>>(xyA, norms, pl, cnts, listA, cntg, nbr);
  rerank_fs_k<<<256, 256, 0, stream>>>(xyA, norms, listB, cntg, nbr);

  mrconv_k<<<1024, 256, 0, stream>>>(xyA, nbr, mr0t,
      (const float*)d_in[5], (const float*)d_in[6], (const float*)d_in[7],
      (const float*)d_in[8], (const float*)d_in[9], xyB);
  mrconv_k<<<1024, 256, 0, stream>>>(xyB, nbr, mr1t,
      (const float*)d_in[11], (const float*)d_in[12], (const float*)d_in[13],
      (const float*)d_in[14], (const float*)d_in[15], xyA);

  fc_k<<<1024, 256, 0, stream>>>(xyA, fct,
      (const float*)d_in[17], (const float*)d_in[18], (const float*)d_in[19],
      (const float*)d_in[20], (const float*)d_in[21], x, y, xyB);

  ffn_k<<<2048, 256, 0, stream>>>(xyB,
      f1t, (const float*)d_in[23], (const float*)d_in[24], (const float*)d_in[25],
      (const float*)d_in[26], (const float*)d_in[27],
      f2t, (const float*)d_in[29], (const float*)d_in[30], (const float*)d_in[31],
      (const float*)d_in[32], (const float*)d_in[33],
      xm, ym, (float*)d_out);
}

// Round 14
// 623.010 us; speedup vs baseline: 1.1449x; 1.1323x over previous
//
#include <hip/hip_runtime.h>
#include <hip/hip_bf16.h>
#include <float.h>
#include <math.h>

#define BB 4
#define N1 4096
#define NT 8192
#define CH 128
#define NBRS 18
#define ZSEL 2.35f
#define LCAP 40
#define EQ 4096.0f
#define GQGAP 6
#define GQCOV 3

typedef __attribute__((ext_vector_type(8))) short s16x8;
typedef __attribute__((ext_vector_type(16))) float f32x16;
typedef __attribute__((ext_vector_type(4))) float f32x4;

__device__ inline unsigned short f2bf(float v) {
  unsigned u = __float_as_uint(v);
  unsigned r = (u + 0x7FFFu + ((u >> 16) & 1u)) >> 16;
  return (unsigned short)r;
}
__device__ inline float bf2f(unsigned short h) {
  return __uint_as_float((unsigned)h << 16);
}
__device__ inline unsigned mapf(float f) {
  unsigned u = __float_as_uint(f);
  return (u & 0x80000000u) ? ~u : (u | 0x80000000u);
}
__device__ inline float gelu_f(float x) {
  return 0.5f * x * (1.0f + erff(x * 0.70710678118654752f));
}

// ---------------------------------------------------------------- transpose
__global__ __launch_bounds__(256) void transpose_k(const float* __restrict__ in,
                                                   float* __restrict__ out,
                                                   int rows, int cols) {
  int t = blockIdx.x * 256 + threadIdx.x;
  if (t < rows * cols) {
    int r = t / cols, c = t % cols;
    out[c * rows + r] = in[t];
  }
}

// --------------------------------------------- split f32 weights -> hi/lo bf16
__global__ __launch_bounds__(256) void wsplit_k(const float* __restrict__ w,
                                                unsigned short* __restrict__ hi,
                                                unsigned short* __restrict__ lo,
                                                int n) {
  int t = blockIdx.x * 256 + threadIdx.x;
  if (t < n) {
    float v = w[t];
    unsigned short h = f2bf(v);
    float r = v - bf2f(h);
    hi[t] = h; lo[t] = f2bf(r);
  }
}

// ------------------------------------------------- concat x,y + squared norms
__global__ __launch_bounds__(256) void norms_concat_k(const float* __restrict__ x,
                                                      const float* __restrict__ y,
                                                      float* __restrict__ xy,
                                                      float* __restrict__ norms) {
  int w = (blockIdx.x * 256 + threadIdx.x) >> 6;
  int lane = threadIdx.x & 63;
  int b = w >> 13, row = w & 8191;
  const float* src = (row < N1) ? (x + ((size_t)b * N1 + row) * CH)
                                : (y + ((size_t)b * N1 + (row - N1)) * CH);
  float2 v = *(const float2*)(src + lane * 2);
  *(float2*)(xy + (size_t)w * CH + lane * 2) = v;
  float s = v.x * v.x + v.y * v.y;
  for (int off = 32; off > 0; off >>= 1) s += __shfl_down(s, off);
  if (lane == 0) norms[w] = s;
}

// ---------------------------------------- build split-bf16 k-major candidate buf
__global__ __launch_bounds__(256) void cbt_k(const float* __restrict__ xy,
                                             unsigned short* __restrict__ cbt) {
  int t = blockIdx.x * 256 + threadIdx.x;
  int u = t >> 15, p = t & 32767;
  const float* src = xy + (size_t)p * CH + u * 8;
  unsigned hw[4], lw[4];
#pragma unroll
  for (int j = 0; j < 4; ++j) {
    float v0 = src[2 * j], v1 = src[2 * j + 1];
    unsigned short h0 = f2bf(v0), h1 = f2bf(v1);
    float r0 = v0 - bf2f(h0);
    float r1 = v1 - bf2f(h1);
    unsigned short l0 = f2bf(r0), l1 = f2bf(r1);
    hw[j] = (unsigned)h0 | ((unsigned)h1 << 16);
    lw[j] = (unsigned)l0 | ((unsigned)l1 << 16);
  }
  *(uint4*)&cbt[((size_t)u * 32768 + p) * 8] = make_uint4(hw[0], hw[1], hw[2], hw[3]);
  *(uint4*)&cbt[((size_t)(u + 16) * 32768 + p) * 8] = make_uint4(lw[0], lw[1], lw[2], lw[3]);
}

// ------------- MFMA knn: threshold-collect to LDS + in-kernel certify/select
__global__ __launch_bounds__(256) void knn4_k(const unsigned short* __restrict__ cbt,
                                              const float* __restrict__ norms,
                                              int* __restrict__ nbr,
                                              int* __restrict__ cntg,
                                              unsigned* __restrict__ listA,
                                              unsigned* __restrict__ listB,
                                              unsigned short* __restrict__ fbl) {
  __shared__ unsigned short __align__(16) cst[2][32][32][8];
  __shared__ float cn_s[2][32];
  __shared__ unsigned lst[128][2][LCAP];
  __shared__ unsigned short lcnt[128][2];
  const int tid = threadIdx.x;
  const int qblk = blockIdx.x, z = blockIdx.y;
  const int b = z >> 2, combo = z & 3;
  const int qoff = (combo <= 1) ? 0 : N1;
  const int coff = (combo == 0 || combo == 3) ? 0 : N1;
  const int w = tid >> 6;
  const int cl = tid & 31;
  const int h = (tid >> 5) & 1;
  const int h4 = 4 * h;
  const int ql = w * 32 + cl;
  const int q = qblk * 128 + ql;
  const size_t qp = (size_t)b * NT + qoff + q;
  const size_t cb0 = (size_t)b * NT + coff;

  const s16x8* cv = (const s16x8*)cbt;
  s16x8 bh[8], bl[8];
#pragma unroll
  for (int s = 0; s < 8; ++s) {
    bh[s] = cv[(size_t)(2 * s + h) * 32768 + qp];
    bl[s] = cv[(size_t)(16 + 2 * s + h) * 32768 + qp];
  }

  const float nq = norms[qp];
  const float Tc = 128.f - ZSEL * sqrtf(256.f + 4.f * nq);
  int cnt = 0;

  const int su = tid >> 5, sc = tid & 31;
  const char* p0 = (const char*)&cbt[((size_t)(su) * 32768 + cb0 + sc) * 8];
  const char* p1 = (const char*)&cbt[((size_t)(8 + su) * 32768 + cb0 + sc) * 8];
  const char* p2 = (const char*)&cbt[((size_t)(16 + su) * 32768 + cb0 + sc) * 8];
  const char* p3 = (const char*)&cbt[((size_t)(24 + su) * 32768 + cb0 + sc) * 8];
  const float* pn = norms + cb0 + tid;

  uint4 st[4]; float cnreg = 0.f;
  st[0] = *(const uint4*)p0; p0 += 512;
  st[1] = *(const uint4*)p1; p1 += 512;
  st[2] = *(const uint4*)p2; p2 += 512;
  st[3] = *(const uint4*)p3; p3 += 512;
  if (tid < 32) { cnreg = *pn; pn += 32; }
  *(uint4*)&cst[0][su][sc][0] = st[0];
  *(uint4*)&cst[0][8 + su][sc][0] = st[1];
  *(uint4*)&cst[0][16 + su][sc][0] = st[2];
  *(uint4*)&cst[0][24 + su][sc][0] = st[3];
  if (tid < 32) cn_s[0][tid] = cnreg;
  __syncthreads();

  int buf = 0;
  for (int t = 0; t < 128; ++t) {
    if (t < 127) {
      st[0] = *(const uint4*)p0; p0 += 512;
      st[1] = *(const uint4*)p1; p1 += 512;
      st[2] = *(const uint4*)p2; p2 += 512;
      st[3] = *(const uint4*)p3; p3 += 512;
      if (tid < 32) { cnreg = *pn; pn += 32; }
    }
    f32x16 acc = {0.f,0.f,0.f,0.f,0.f,0.f,0.f,0.f,0.f,0.f,0.f,0.f,0.f,0.f,0.f,0.f};
#pragma unroll
    for (int s = 0; s < 8; ++s) {
      s16x8 a0 = *(const s16x8*)&cst[buf][2 * s + h][cl][0];
      s16x8 a1 = *(const s16x8*)&cst[buf][16 + 2 * s + h][cl][0];
      acc = __builtin_amdgcn_mfma_f32_32x32x16_bf16(a0, bh[s], acc, 0, 0, 0);
      acc = __builtin_amdgcn_mfma_f32_32x32x16_bf16(a0, bl[s], acc, 0, 0, 0);
      acc = __builtin_amdgcn_mfma_f32_32x32x16_bf16(a1, bh[s], acc, 0, 0, 0);
    }
    float4 c0 = *(const float4*)&cn_s[buf][h4];
    float4 c1 = *(const float4*)&cn_s[buf][8 + h4];
    float4 c2 = *(const float4*)&cn_s[buf][16 + h4];
    float4 c3 = *(const float4*)&cn_s[buf][24 + h4];
    const float cw[16] = {c0.x, c0.y, c0.z, c0.w, c1.x, c1.y, c1.z, c1.w,
                          c2.x, c2.y, c2.z, c2.w, c3.x, c3.y, c3.z, c3.w};
    const int ib = t * 32 + h4;
#pragma unroll
    for (int g = 0; g < 4; ++g) {
#pragma unroll
      for (int rr = 0; rr < 4; ++rr) {
        const int r = g * 4 + rr;
        float s = fmaf(-2.0f, acc[r], cw[r]);
        if (s <= Tc) {
          int e = (int)((Tc - s) * EQ);
          e = e > 0xFFFFF ? 0xFFFFF : e;
          unsigned key = ((unsigned)e << 12) | (unsigned)(4095 - (ib + g * 8 + rr));
          if (cnt < LCAP) lst[ql][h][cnt] = key;
          ++cnt;
        }
      }
    }
    if (t < 127) {
      *(uint4*)&cst[buf ^ 1][su][sc][0] = st[0];
      *(uint4*)&cst[buf ^ 1][8 + su][sc][0] = st[1];
      *(uint4*)&cst[buf ^ 1][16 + su][sc][0] = st[2];
      *(uint4*)&cst[buf ^ 1][24 + su][sc][0] = st[3];
      if (tid < 32) cn_s[buf ^ 1][tid] = cnreg;
    }
    __syncthreads();
    buf ^= 1;
  }
  lcnt[ql][h] = (unsigned short)cnt;
  __syncthreads();

  if (tid < 128) {
    const int mq = tid;
    const int gq = z * 4096 + qblk * 128 + mq;
    const int c0 = lcnt[mq][0], c1 = lcnt[mq][1];
    const bool over = (c0 > LCAP) || (c1 > LCAP);
    const int n0 = c0 > LCAP ? LCAP : c0;
    const int n1 = c1 > LCAP ? LCAP : c1;
    const int m = n0 + n1;
    unsigned top[10];
#pragma unroll
    for (int j = 0; j < 10; ++j) top[j] = 0u;
    for (int li = 0; li < 2; ++li) {
      const int n = li ? n1 : n0;
      for (int i = 0; i < n; ++i) {
        unsigned key = lst[mq][li][i];
        if (key > top[9]) {
#pragma unroll
          for (int j = 0; j < 10; ++j) {
            bool sw = key > top[j];
            unsigned tv = top[j];
            top[j] = sw ? key : tv;
            key = sw ? tv : key;
          }
        }
      }
    }
    const unsigned e8 = top[8] >> 12, e9 = top[9] >> 12;
    const bool cov = !over && (m >= 9) && (e8 >= GQCOV);
    const bool ok = cov && (m == 9 || (e8 - e9) >= GQGAP);
    const int qg = qblk * 128 + mq;
    const int row = (combo <= 1) ? qg : (N1 + qg);
    const int slot = (combo == 0 || combo == 2) ? 0 : 9;
    const int ioff = (combo == 1 || combo == 2) ? N1 : 0;
    int* dst = nbr + ((size_t)b * NT + row) * NBRS + slot;
    if (ok) {
#pragma unroll
      for (int s = 0; s < 9; ++s)
        dst[s] = (int)(4095u - (top[s] & 0xFFFu)) + ioff;
    } else if (!cov || m > 64) {
      int idx = atomicAdd(&cntg[1], 1);
      listB[idx] = (unsigned)gq;
    } else {
      int idx = atomicAdd(&cntg[0], 1);
      listA[idx] = ((unsigned)m << 16) | (unsigned)gq;
      unsigned short* fp = fbl + (size_t)gq * 64;
      int p = 0;
      for (int i = 0; i < n0; ++i) fp[p++] = (unsigned short)(4095u - (lst[mq][0][i] & 0xFFFu));
      for (int i = 0; i < n1; ++i) fp[p++] = (unsigned short)(4095u - (lst[mq][1][i] & 0xFFFu));
    }
  }
}

// ------- rerank_sl: grid-stride over compacted shortlist queries (wave each)
__global__ __launch_bounds__(256) void rerank_sl_k(const float* __restrict__ xy,
                                                   const float* __restrict__ norms,
                                                   const unsigned short* __restrict__ fbl,
                                                   const unsigned* __restrict__ listA,
                                                   const int* __restrict__ cntg,
                                                   int* __restrict__ nbr) {
  const int lane = threadIdx.x & 63;
  const int wv = threadIdx.x >> 6;
  const int nA = cntg[0];
  for (int i = blockIdx.x * 4 + wv; i < nA; i += gridDim.x * 4) {
    const unsigned ent = listA[i];
    const int gq = (int)(ent & 0xffffu);
    const int m = (int)(ent >> 16);
    const int z = gq >> 12, q = gq & 4095;
    const int b = z >> 2, combo = z & 3;
    const int qoff = (combo <= 1) ? 0 : N1;
    const int coff = (combo == 0 || combo == 3) ? 0 : N1;
    const size_t cq = (size_t)b * NT + coff;
    const int row = (combo <= 1) ? q : (N1 + q);
    const int slot = (combo == 0 || combo == 2) ? 0 : 9;
    const int ioff = (combo == 1 || combo == 2) ? N1 : 0;
    int* dst = nbr + ((size_t)b * NT + row) * NBRS + slot;
    const float* qrow = xy + ((size_t)b * NT + qoff + q) * CH;

    int ci = 0; float de = FLT_MAX;
    if (lane < m) {
      ci = (int)fbl[(size_t)gq * 64 + lane];
      const float* crow = xy + (cq + ci) * CH;
      const float cnv = norms[cq + ci];
      float a0 = 0.f, a1 = 0.f, a2 = 0.f, a3 = 0.f;
#pragma unroll
      for (int k = 0; k < 32; ++k) {
        float4 qv = *(const float4*)(qrow + k * 4);
        float4 cv2 = *(const float4*)(crow + k * 4);
        a0 = fmaf(qv.x, cv2.x, a0); a1 = fmaf(qv.y, cv2.y, a1);
        a2 = fmaf(qv.z, cv2.z, a2); a3 = fmaf(qv.w, cv2.w, a3);
      }
      de = cnv - 2.0f * ((a0 + a1) + (a2 + a3));
    }
    unsigned long long key = ((unsigned long long)mapf(de) << 32) | (unsigned)ci;
    if (lane >= m) key = ~0ull;
    int xr = 0;
#pragma unroll 1
    for (int k = 0; k < m; ++k) {
      unsigned long long kk = __shfl(key, k);
      xr += (kk < key) ? 1 : 0;
    }
    if (lane < m && xr < 9) dst[xr] = ci + ioff;
  }
}

// ------- rerank_fs: grid-stride over full-scan queries (one BLOCK each)
__global__ __launch_bounds__(256) void rerank_fs_k(const float* __restrict__ xy,
                                                   const float* __restrict__ norms,
                                                   const unsigned* __restrict__ listB,
                                                   const int* __restrict__ cntg,
                                                   int* __restrict__ nbr) {
  __shared__ unsigned long long ms[4][576];
  __shared__ unsigned long long wk[36];
  const int tid = threadIdx.x;
  const int lane = tid & 63, wv = tid >> 6;
  const int nB = cntg[1];
  for (int i = blockIdx.x; i < nB; i += gridDim.x) {
    const int gq = (int)listB[i];
    const int z = gq >> 12, q = gq & 4095;
    const int b = z >> 2, combo = z & 3;
    const int qoff = (combo <= 1) ? 0 : N1;
    const int coff = (combo == 0 || combo == 3) ? 0 : N1;
    const size_t cq = (size_t)b * NT + coff;
    const int row = (combo <= 1) ? q : (N1 + q);
    const int slot = (combo == 0 || combo == 2) ? 0 : 9;
    const int ioff = (combo == 1 || combo == 2) ? N1 : 0;
    int* dst = nbr + ((size_t)b * NT + row) * NBRS + slot;
    const float* qrow = xy + ((size_t)b * NT + qoff + q) * CH;

    unsigned long long bl9[9];
#pragma unroll
    for (int j = 0; j < 9; ++j) bl9[j] = ~0ull;
    for (int it = 0; it < 16; ++it) {
      const int cc = (it * 4 + wv) * 64 + lane;
      const float* crow = xy + (cq + cc) * CH;
      float a0 = 0.f, a1 = 0.f, a2 = 0.f, a3 = 0.f;
#pragma unroll
      for (int k = 0; k < 32; ++k) {
        float4 qv = *(const float4*)(qrow + k * 4);
        float4 cv2 = *(const float4*)(crow + k * 4);
        a0 = fmaf(qv.x, cv2.x, a0); a1 = fmaf(qv.y, cv2.y, a1);
        a2 = fmaf(qv.z, cv2.z, a2); a3 = fmaf(qv.w, cv2.w, a3);
      }
      float d2v = norms[cq + cc] - 2.0f * ((a0 + a1) + (a2 + a3));
      unsigned long long key = ((unsigned long long)mapf(d2v) << 32) | (unsigned)cc;
      if (key < bl9[8]) {
#pragma unroll
        for (int jj = 0; jj < 9; ++jj) {
          bool sw = key < bl9[jj];
          unsigned long long tv = bl9[jj];
          bl9[jj] = sw ? key : tv;
          key = sw ? tv : key;
        }
      }
    }
#pragma unroll
    for (int s = 0; s < 9; ++s) ms[wv][lane * 9 + s] = bl9[s];
    int ptr = 0;
    for (int s = 0; s < 9; ++s) {
      unsigned long long hd = ms[wv][lane * 9 + ptr];
      unsigned long long mn = hd;
#pragma unroll
      for (int off = 1; off < 64; off <<= 1) {
        unsigned long long ot = __shfl_xor(mn, off);
        mn = (ot < mn) ? ot : mn;
      }
      unsigned long long wm = __ballot(hd == mn);
      int wl = __ffsll(wm) - 1;
      if (lane == wl) ptr++;
      if (lane == 0) wk[wv * 9 + s] = mn;
    }
    __syncthreads();
    if (wv == 0) {
      unsigned long long key = (lane < 36) ? wk[lane] : ~0ull;
      int xr = 0;
#pragma unroll 1
      for (int k = 0; k < 36; ++k) {
        unsigned long long kk = __shfl(key, k);
        xr += (kk < key) ? 1 : 0;
      }
      if (lane < 36 && xr < 9) dst[xr] = (int)(unsigned)(key & 0xffffffffull) + ioff;
    }
    __syncthreads();
  }
}

// ------------------------------------------- mrconv: gather+max+linear+BN+gelu
__global__ __launch_bounds__(256) void mrconv_k(const float* __restrict__ in,
                                                const int* __restrict__ nbr,
                                                const float* __restrict__ Wt,
                                                const float* __restrict__ bias,
                                                const float* __restrict__ gam,
                                                const float* __restrict__ bet,
                                                const float* __restrict__ mean,
                                                const float* __restrict__ var,
                                                float* __restrict__ out) {
  __shared__ float h[32][260];
  const int tid = threadIdx.x;
  const int pt0 = blockIdx.x * 32;
  {
    const int w = tid >> 6, lane = tid & 63;
    for (int pp = 0; pp < 8; ++pp) {
      const int p = w * 8 + pp;
      const int n = pt0 + p;
      const int b = n >> 13;
      const float* frow = in + (size_t)n * CH;
      float2 f2 = *(const float2*)(frow + lane * 2);
      float mx = -FLT_MAX, my = -FLT_MAX;
      const int* nb = nbr + (size_t)n * NBRS;
      for (int j = 0; j < NBRS; ++j) {
        int idx = nb[j];
        const float* vrow = in + ((size_t)b * NT + idx) * CH;
        float2 v2 = *(const float2*)(vrow + lane * 2);
        mx = fmaxf(mx, v2.x - f2.x);
        my = fmaxf(my, v2.y - f2.y);
      }
      h[p][lane * 4 + 0] = f2.x; h[p][lane * 4 + 1] = mx;
      h[p][lane * 4 + 2] = f2.y; h[p][lane * 4 + 3] = my;
    }
  }
  __syncthreads();
  const int o = tid & 127, gg = tid >> 7;
  float acc[16];
#pragma unroll
  for (int p = 0; p < 16; ++p) acc[p] = 0.f;
  for (int k = 0; k < 256; k += 4) {
    float w0 = Wt[(k + 0) * CH + o], w1 = Wt[(k + 1) * CH + o];
    float w2 = Wt[(k + 2) * CH + o], w3 = Wt[(k + 3) * CH + o];
#pragma unroll
    for (int p = 0; p < 16; ++p) {
      float4 hv = *(const float4*)&h[gg * 16 + p][k];
      acc[p] = fmaf(hv.x, w0, acc[p]);
      acc[p] = fmaf(hv.y, w1, acc[p]);
      acc[p] = fmaf(hv.z, w2, acc[p]);
      acc[p] = fmaf(hv.w, w3, acc[p]);
    }
  }
  const float sc = gam[o] / sqrtf(var[o] + 1e-5f);
  const float bs = bias[o], mo = mean[o], be = bet[o];
#pragma unroll
  for (int p = 0; p < 16; ++p) {
    const int n = pt0 + gg * 16 + p;
    float hv = acc[p] + bs;
    float bn = (hv - mo) * sc + be;
    float gl = 0.5f * bn * (1.0f + erff(bn * 0.70710678118654752f));
    out[(size_t)n * CH + o] = gl + h[gg * 16 + p][2 * o];
  }
}

// --------- fc2: MFMA linear 128->128 + BN + residual. 16 points/block.
__global__ __launch_bounds__(256) void fc2_k(const float* __restrict__ in,
                                             const unsigned short* __restrict__ Whi,
                                             const unsigned short* __restrict__ Wlo,
                                             const float* __restrict__ bias,
                                             const float* __restrict__ gam,
                                             const float* __restrict__ bet,
                                             const float* __restrict__ mean,
                                             const float* __restrict__ var,
                                             const float* __restrict__ xres,
                                             const float* __restrict__ yres,
                                             float* __restrict__ out) {
  __shared__ unsigned short __align__(16) aHi[16][16][8];
  __shared__ unsigned short __align__(16) aLo[16][16][8];
  const int tid = threadIdx.x;
  const int pt0 = blockIdx.x * 16;
  {
    const int row = tid >> 4, ku = tid & 15;
    const float* src = in + (size_t)(pt0 + row) * CH + ku * 8;
    unsigned hw[4], lw[4];
#pragma unroll
    for (int j = 0; j < 4; ++j) {
      float v0 = src[2 * j], v1 = src[2 * j + 1];
      unsigned short h0 = f2bf(v0), h1 = f2bf(v1);
      float r0 = v0 - bf2f(h0), r1 = v1 - bf2f(h1);
      hw[j] = (unsigned)h0 | ((unsigned)f2bf(v1) << 16);
      hw[j] = (unsigned)h0 | ((unsigned)h1 << 16);
      lw[j] = (unsigned)f2bf(r0) | ((unsigned)f2bf(r1) << 16);
    }
    *(uint4*)&aHi[ku][row][0] = make_uint4(hw[0], hw[1], hw[2], hw[3]);
    *(uint4*)&aLo[ku][row][0] = make_uint4(lw[0], lw[1], lw[2], lw[3]);
  }
  __syncthreads();
  const int lane = tid & 63, w = tid >> 6;
  const int r16 = lane & 15, kg = lane >> 4;
  f32x4 acc[2] = {{0.f,0.f,0.f,0.f}, {0.f,0.f,0.f,0.f}};
#pragma unroll
  for (int ks = 0; ks < 4; ++ks) {
    s16x8 ah = *(const s16x8*)&aHi[ks * 4 + kg][r16][0];
    s16x8 al = *(const s16x8*)&aLo[ks * 4 + kg][r16][0];
#pragma unroll
    for (int cb = 0; cb < 2; ++cb) {
      const int o = w * 32 + cb * 16 + r16;
      s16x8 bh2 = *(const s16x8*)(Whi + o * 128 + ks * 32 + kg * 8);
      s16x8 bl2 = *(const s16x8*)(Wlo + o * 128 + ks * 32 + kg * 8);
      acc[cb] = __builtin_amdgcn_mfma_f32_16x16x32_bf16(ah, bh2, acc[cb], 0, 0, 0);
      acc[cb] = __builtin_amdgcn_mfma_f32_16x16x32_bf16(ah, bl2, acc[cb], 0, 0, 0);
      acc[cb] = __builtin_amdgcn_mfma_f32_16x16x32_bf16(al, bh2, acc[cb], 0, 0, 0);
    }
  }
#pragma unroll
  for (int cb = 0; cb < 2; ++cb) {
    const int o = w * 32 + cb * 16 + r16;
    const float sc = gam[o] / sqrtf(var[o] + 1e-5f);
    const float bs = bias[o], mo = mean[o], be = bet[o];
#pragma unroll
    for (int rg = 0; rg < 4; ++rg) {
      const int row = kg * 4 + rg;
      const int n = pt0 + row;
      const int b = n >> 13, prow = n & 8191;
      float bn = (acc[cb][rg] + bs - mo) * sc + be;
      float res = (prow < N1) ? xres[((size_t)b * N1 + prow) * CH + o]
                              : yres[((size_t)b * N1 + prow - N1) * CH + o];
      out[(size_t)n * CH + o] = bn + res;
    }
  }
}

// --------- ffn2: MFMA fused 128->512(GELU)->128 + BN + res + mask.
__global__ __launch_bounds__(256) void ffn2_k(const float* __restrict__ u,
                                              const unsigned short* __restrict__ W1hi,
                                              const unsigned short* __restrict__ W1lo,
                                              const float* __restrict__ b1,
                                              const float* __restrict__ g1,
                                              const float* __restrict__ be1,
                                              const float* __restrict__ m1,
                                              const float* __restrict__ v1,
                                              const unsigned short* __restrict__ W2hi,
                                              const unsigned short* __restrict__ W2lo,
                                              const float* __restrict__ b2,
                                              const float* __restrict__ g2,
                                              const float* __restrict__ be2,
                                              const float* __restrict__ m2,
                                              const float* __restrict__ v2,
                                              const float* __restrict__ xmask,
                                              const float* __restrict__ ymask,
                                              float* __restrict__ outbuf) {
  __shared__ unsigned short __align__(16) aHi[16][16][8];
  __shared__ unsigned short __align__(16) aLo[16][16][8];
  __shared__ unsigned short __align__(16) hHi[64][16][8];
  __shared__ unsigned short __align__(16) hLo[64][16][8];
  const int tid = threadIdx.x;
  const int pt0 = blockIdx.x * 16;
  {
    const int row = tid >> 4, ku = tid & 15;
    const float* src = u + (size_t)(pt0 + row) * CH + ku * 8;
    unsigned hw[4], lw[4];
#pragma unroll
    for (int j = 0; j < 4; ++j) {
      float v0 = src[2 * j], v1 = src[2 * j + 1];
      unsigned short h0 = f2bf(v0), h1 = f2bf(v1);
      float r0 = v0 - bf2f(h0), r1 = v1 - bf2f(h1);
      hw[j] = (unsigned)h0 | ((unsigned)h1 << 16);
      lw[j] = (unsigned)f2bf(r0) | ((unsigned)f2bf(r1) << 16);
    }
    *(uint4*)&aHi[ku][row][0] = make_uint4(hw[0], hw[1], hw[2], hw[3]);
    *(uint4*)&aLo[ku][row][0] = make_uint4(lw[0], lw[1], lw[2], lw[3]);
  }
  __syncthreads();
  const int lane = tid & 63, w = tid >> 6;
  const int r16 = lane & 15, kg = lane >> 4;
  // ---- stage 1: 128 -> 512, wave covers 128 output cols (8 colblocks)
  {
    f32x4 acc[8];
#pragma unroll
    for (int cb = 0; cb < 8; ++cb) acc[cb] = {0.f, 0.f, 0.f, 0.f};
#pragma unroll
    for (int ks = 0; ks < 4; ++ks) {
      s16x8 ah = *(const s16x8*)&aHi[ks * 4 + kg][r16][0];
      s16x8 al = *(const s16x8*)&aLo[ks * 4 + kg][r16][0];
#pragma unroll
      for (int cb = 0; cb < 8; ++cb) {
        const int o = w * 128 + cb * 16 + r16;
        s16x8 bh2 = *(const s16x8*)(W1hi + o * 128 + ks * 32 + kg * 8);
        s16x8 bl2 = *(const s16x8*)(W1lo + o * 128 + ks * 32 + kg * 8);
        acc[cb] = __builtin_amdgcn_mfma_f32_16x16x32_bf16(ah, bh2, acc[cb], 0, 0, 0);
        acc[cb] = __builtin_amdgcn_mfma_f32_16x16x32_bf16(ah, bl2, acc[cb], 0, 0, 0);
        acc[cb] = __builtin_amdgcn_mfma_f32_16x16x32_bf16(al, bh2, acc[cb], 0, 0, 0);
      }
    }
#pragma unroll
    for (int cb = 0; cb < 8; ++cb) {
      const int o = w * 128 + cb * 16 + r16;
      const float sc = g1[o] / sqrtf(v1[o] + 1e-5f);
      const float bs = b1[o], mo = m1[o], be = be1[o];
#pragma unroll
      for (int rg = 0; rg < 4; ++rg) {
        const int row = kg * 4 + rg;
        float bn = (acc[cb][rg] + bs - mo) * sc + be;
        float gl = gelu_f(bn);
        unsigned short hb = f2bf(gl);
        float rr = gl - bf2f(hb);
        hHi[o >> 3][row][o & 7] = hb;
        hLo[o >> 3][row][o & 7] = f2bf(rr);
      }
    }
  }
  __syncthreads();
  // ---- stage 2: 512 -> 128, wave covers 32 output cols (2 colblocks)
  {
    f32x4 acc[2] = {{0.f,0.f,0.f,0.f}, {0.f,0.f,0.f,0.f}};
#pragma unroll
    for (int ks = 0; ks < 16; ++ks) {
      s16x8 ah = *(const s16x8*)&hHi[ks * 4 + kg][r16][0];
      s16x8 al = *(const s16x8*)&hLo[ks * 4 + kg][r16][0];
#pragma unroll
      for (int cb = 0; cb < 2; ++cb) {
        const int o = w * 32 + cb * 16 + r16;
        s16x8 bh2 = *(const s16x8*)(W2hi + o * 512 + ks * 32 + kg * 8);
        s16x8 bl2 = *(const s16x8*)(W2lo + o * 512 + ks * 32 + kg * 8);
        acc[cb] = __builtin_amdgcn_mfma_f32_16x16x32_bf16(ah, bh2, acc[cb], 0, 0, 0);
        acc[cb] = __builtin_amdgcn_mfma_f32_16x16x32_bf16(ah, bl2, acc[cb], 0, 0, 0);
        acc[cb] = __builtin_amdgcn_mfma_f32_16x16x32_bf16(al, bh2, acc[cb], 0, 0, 0);
      }
    }
#pragma unroll
    for (int cb = 0; cb < 2; ++cb) {
      const int o = w * 32 + cb * 16 + r16;
      const float sc = g2[o] / sqrtf(v2[o] + 1e-5f);
      const float bs = b2[o], mo = m2[o], be = be2[o];
#pragma unroll
      for (int rg = 0; rg < 4; ++rg) {
        const int row = kg * 4 + rg;
        const int n = pt0 + row;
        const int b = n >> 13, prow = n & 8191;
        float bn = (acc[cb][rg] + bs - mo) * sc + be;
        float gl = gelu_f(bn);
        float res = u[(size_t)n * CH + o];
        float msk; size_t oidx;
        if (prow < N1) {
          msk = xmask[(size_t)b * N1 + prow];
          oidx = ((size_t)b * N1 + prow) * CH + o;
        } else {
          msk = ymask[(size_t)b * N1 + prow - N1];
          oidx = (size_t)BB * N1 * CH + ((size_t)b * N1 + prow - N1) * CH + o;
        }
        outbuf[oidx] = (gl + res) * msk;
      }
    }
  }
}

// ---------------------------------------------------------------------------
extern "C" void kernel_launch(void* const* d_in, const int* in_sizes, int n_in,
                              void* d_out, int out_size, void* d_ws, size_t ws_size,
                              hipStream_t stream) {
  const float* x  = (const float*)d_in[0];
  const float* y  = (const float*)d_in[1];
  const float* xm = (const float*)d_in[2];
  const float* ym = (const float*)d_in[3];
  const float* mr0W = (const float*)d_in[4];
  const float* mr1W = (const float*)d_in[10];
  const float* fcW  = (const float*)d_in[16];
  const float* f1W  = (const float*)d_in[22];
  const float* f2W  = (const float*)d_in[28];

  char* ws = (char*)d_ws;
  float*          xyA   = (float*)(ws + 0);
  unsigned short* cbt   = (unsigned short*)(ws + 16777216);
  float*          xyB   = (float*)(ws + 16777216);
  float*          norms = (float*)(ws + 33554432);
  int*            cntg  = (int*)(ws + 33685504);
  unsigned*       listA = (unsigned*)(ws + 33689600);
  unsigned*       listB = (unsigned*)(ws + 33951744);
  unsigned short* fbl   = (unsigned short*)(ws + 34213888);  // 8.39 MB
  int*            nbr   = (int*)(ws + 42602496);             // 2.36 MB
  float*          mr0t  = (float*)(ws + 44961792);           // 128 KB
  float*          mr1t  = (float*)(ws + 45092864);           // 128 KB
  unsigned short* fcWhi = (unsigned short*)(ws + 45223936);  // 32 KB
  unsigned short* fcWlo = (unsigned short*)(ws + 45256704);  // 32 KB
  unsigned short* f1hi  = (unsigned short*)(ws + 45289472);  // 128 KB
  unsigned short* f1lo  = (unsigned short*)(ws + 45420544);  // 128 KB
  unsigned short* f2hi  = (unsigned short*)(ws + 45551616);  // 128 KB
  unsigned short* f2lo  = (unsigned short*)(ws + 45682688);  // 128 KB (end 45.81 MB)

  hipMemsetAsync(cntg, 0, 8, stream);

  transpose_k<<<(128 * 256 + 255) / 256, 256, 0, stream>>>(mr0W, mr0t, 128, 256);
  transpose_k<<<(128 * 256 + 255) / 256, 256, 0, stream>>>(mr1W, mr1t, 128, 256);
  wsplit_k<<<64, 256, 0, stream>>>(fcW, fcWhi, fcWlo, 128 * 128);
  wsplit_k<<<256, 256, 0, stream>>>(f1W, f1hi, f1lo, 512 * 128);
  wsplit_k<<<256, 256, 0, stream>>>(f2W, f2hi, f2lo, 128 * 512);

  norms_concat_k<<<8192, 256, 0, stream>>>(x, y, xyA, norms);
  cbt_k<<<2048, 256, 0, stream>>>(xyA, cbt);
  knn4_k<<<dim3(32, 16), 256, 0, stream>>>(cbt, norms, nbr, cntg, listA, listB, fbl);
  rerank_sl_k<<<256, 256, 0, stream>>>(xyA, norms, fbl, listA, cntg, nbr);
  rerank_fs_k<<<256, 256, 0, stream>>>(xyA, norms, listB, cntg, nbr);

  mrconv_k<<<1024, 256, 0, stream>>>(xyA, nbr, mr0t,
      (const float*)d_in[5], (const float*)d_in[6], (const float*)d_in[7],
      (const float*)d_in[8], (const float*)d_in[9], xyB);
  mrconv_k<<<1024, 256, 0, stream>>>(xyB, nbr, mr1t,
      (const float*)d_in[11], (const float*)d_in[12], (const float*)d_in[13],
      (const float*)d_in[14], (const float*)d_in[15], xyA);

  fc2_k<<<2048, 256, 0, stream>>>(xyA, fcWhi, fcWlo,
      (const float*)d_in[17], (const float*)d_in[18], (const float*)d_in[19],
      (const float*)d_in[20], (const float*)d_in[21], x, y, xyB);

  ffn2_k<<<2048, 256, 0, stream>>>(xyB,
      f1hi, f1lo, (const float*)d_in[23], (const float*)d_in[24], (const float*)d_in[25],
      (const float*)d_in[26], (const float*)d_in[27],
      f2hi, f2lo, (const float*)d_in[29], (const float*)d_in[30], (const float*)d_in[31],
      (const float*)d_in[32], (const float*)d_in[33],
      xm, ym, (float*)d_out);
}

// Round 15
// 576.115 us; speedup vs baseline: 1.2381x; 1.0814x over previous
//
#include <hip/hip_runtime.h>
#include <hip/hip_bf16.h>
#include <float.h>
#include <math.h>

#define BB 4
#define N1 4096
#define NT 8192
#define CH 128
#define NBRS 18
#define ZSEL 2.35f
#define LCAP 40
#define EQ 4096.0f
#define GQGAP 6
#define GQCOV 3

typedef __attribute__((ext_vector_type(8))) short s16x8;
typedef __attribute__((ext_vector_type(16))) float f32x16;
typedef __attribute__((ext_vector_type(4))) float f32x4;

__device__ inline unsigned short f2bf(float v) {
  unsigned u = __float_as_uint(v);
  unsigned r = (u + 0x7FFFu + ((u >> 16) & 1u)) >> 16;
  return (unsigned short)r;
}
__device__ inline float bf2f(unsigned short h) {
  return __uint_as_float((unsigned)h << 16);
}
__device__ inline unsigned mapf(float f) {
  unsigned u = __float_as_uint(f);
  return (u & 0x80000000u) ? ~u : (u | 0x80000000u);
}
__device__ inline float gelu_f(float x) {
  return 0.5f * x * (1.0f + erff(x * 0.70710678118654752f));
}

// --------------------------------------------- split f32 weights -> hi/lo bf16
__global__ __launch_bounds__(256) void wsplit_k(const float* __restrict__ w,
                                                unsigned short* __restrict__ hi,
                                                unsigned short* __restrict__ lo,
                                                int n) {
  int t = blockIdx.x * 256 + threadIdx.x;
  if (t < n) {
    float v = w[t];
    unsigned short h = f2bf(v);
    float r = v - bf2f(h);
    hi[t] = h; lo[t] = f2bf(r);
  }
}

// ------------------------------------------------- concat x,y + squared norms
__global__ __launch_bounds__(256) void norms_concat_k(const float* __restrict__ x,
                                                      const float* __restrict__ y,
                                                      float* __restrict__ xy,
                                                      float* __restrict__ norms) {
  int w = (blockIdx.x * 256 + threadIdx.x) >> 6;
  int lane = threadIdx.x & 63;
  int b = w >> 13, row = w & 8191;
  const float* src = (row < N1) ? (x + ((size_t)b * N1 + row) * CH)
                                : (y + ((size_t)b * N1 + (row - N1)) * CH);
  float2 v = *(const float2*)(src + lane * 2);
  *(float2*)(xy + (size_t)w * CH + lane * 2) = v;
  float s = v.x * v.x + v.y * v.y;
  for (int off = 32; off > 0; off >>= 1) s += __shfl_down(s, off);
  if (lane == 0) norms[w] = s;
}

// ---------------------------------------- build split-bf16 k-major candidate buf
__global__ __launch_bounds__(256) void cbt_k(const float* __restrict__ xy,
                                             unsigned short* __restrict__ cbt) {
  int t = blockIdx.x * 256 + threadIdx.x;
  int u = t >> 15, p = t & 32767;
  const float* src = xy + (size_t)p * CH + u * 8;
  unsigned hw[4], lw[4];
#pragma unroll
  for (int j = 0; j < 4; ++j) {
    float v0 = src[2 * j], v1 = src[2 * j + 1];
    unsigned short h0 = f2bf(v0), h1 = f2bf(v1);
    float r0 = v0 - bf2f(h0);
    float r1 = v1 - bf2f(h1);
    unsigned short l0 = f2bf(r0), l1 = f2bf(r1);
    hw[j] = (unsigned)h0 | ((unsigned)h1 << 16);
    lw[j] = (unsigned)l0 | ((unsigned)l1 << 16);
  }
  *(uint4*)&cbt[((size_t)u * 32768 + p) * 8] = make_uint4(hw[0], hw[1], hw[2], hw[3]);
  *(uint4*)&cbt[((size_t)(u + 16) * 32768 + p) * 8] = make_uint4(lw[0], lw[1], lw[2], lw[3]);
}

// ------------- MFMA knn: threshold-collect to LDS + in-kernel certify/select
__global__ __launch_bounds__(256) void knn4_k(const unsigned short* __restrict__ cbt,
                                              const float* __restrict__ norms,
                                              int* __restrict__ nbr,
                                              int* __restrict__ cntg,
                                              unsigned* __restrict__ listA,
                                              unsigned* __restrict__ listB,
                                              unsigned short* __restrict__ fbl) {
  __shared__ unsigned short __align__(16) cst[2][32][32][8];
  __shared__ float cn_s[2][32];
  __shared__ unsigned lst[128][2][LCAP];
  __shared__ unsigned short lcnt[128][2];
  const int tid = threadIdx.x;
  const int qblk = blockIdx.x, z = blockIdx.y;
  const int b = z >> 2, combo = z & 3;
  const int qoff = (combo <= 1) ? 0 : N1;
  const int coff = (combo == 0 || combo == 3) ? 0 : N1;
  const int w = tid >> 6;
  const int cl = tid & 31;
  const int h = (tid >> 5) & 1;
  const int h4 = 4 * h;
  const int ql = w * 32 + cl;
  const int q = qblk * 128 + ql;
  const size_t qp = (size_t)b * NT + qoff + q;
  const size_t cb0 = (size_t)b * NT + coff;

  const s16x8* cv = (const s16x8*)cbt;
  s16x8 bh[8], bl[8];
#pragma unroll
  for (int s = 0; s < 8; ++s) {
    bh[s] = cv[(size_t)(2 * s + h) * 32768 + qp];
    bl[s] = cv[(size_t)(16 + 2 * s + h) * 32768 + qp];
  }

  const float nq = norms[qp];
  const float Tc = 128.f - ZSEL * sqrtf(256.f + 4.f * nq);
  int cnt = 0;

  const int su = tid >> 5, sc = tid & 31;
  const char* p0 = (const char*)&cbt[((size_t)(su) * 32768 + cb0 + sc) * 8];
  const char* p1 = (const char*)&cbt[((size_t)(8 + su) * 32768 + cb0 + sc) * 8];
  const char* p2 = (const char*)&cbt[((size_t)(16 + su) * 32768 + cb0 + sc) * 8];
  const char* p3 = (const char*)&cbt[((size_t)(24 + su) * 32768 + cb0 + sc) * 8];
  const float* pn = norms + cb0 + tid;

  uint4 st[4]; float cnreg = 0.f;
  st[0] = *(const uint4*)p0; p0 += 512;
  st[1] = *(const uint4*)p1; p1 += 512;
  st[2] = *(const uint4*)p2; p2 += 512;
  st[3] = *(const uint4*)p3; p3 += 512;
  if (tid < 32) { cnreg = *pn; pn += 32; }
  *(uint4*)&cst[0][su][sc][0] = st[0];
  *(uint4*)&cst[0][8 + su][sc][0] = st[1];
  *(uint4*)&cst[0][16 + su][sc][0] = st[2];
  *(uint4*)&cst[0][24 + su][sc][0] = st[3];
  if (tid < 32) cn_s[0][tid] = cnreg;
  __syncthreads();

  int buf = 0;
  for (int t = 0; t < 128; ++t) {
    if (t < 127) {
      st[0] = *(const uint4*)p0; p0 += 512;
      st[1] = *(const uint4*)p1; p1 += 512;
      st[2] = *(const uint4*)p2; p2 += 512;
      st[3] = *(const uint4*)p3; p3 += 512;
      if (tid < 32) { cnreg = *pn; pn += 32; }
    }
    f32x16 acc = {0.f,0.f,0.f,0.f,0.f,0.f,0.f,0.f,0.f,0.f,0.f,0.f,0.f,0.f,0.f,0.f};
#pragma unroll
    for (int s = 0; s < 8; ++s) {
      s16x8 a0 = *(const s16x8*)&cst[buf][2 * s + h][cl][0];
      s16x8 a1 = *(const s16x8*)&cst[buf][16 + 2 * s + h][cl][0];
      acc = __builtin_amdgcn_mfma_f32_32x32x16_bf16(a0, bh[s], acc, 0, 0, 0);
      acc = __builtin_amdgcn_mfma_f32_32x32x16_bf16(a0, bl[s], acc, 0, 0, 0);
      acc = __builtin_amdgcn_mfma_f32_32x32x16_bf16(a1, bh[s], acc, 0, 0, 0);
    }
    float4 c0 = *(const float4*)&cn_s[buf][h4];
    float4 c1 = *(const float4*)&cn_s[buf][8 + h4];
    float4 c2 = *(const float4*)&cn_s[buf][16 + h4];
    float4 c3 = *(const float4*)&cn_s[buf][24 + h4];
    const float cw[16] = {c0.x, c0.y, c0.z, c0.w, c1.x, c1.y, c1.z, c1.w,
                          c2.x, c2.y, c2.z, c2.w, c3.x, c3.y, c3.z, c3.w};
    const int ib = t * 32 + h4;
#pragma unroll
    for (int g = 0; g < 4; ++g) {
#pragma unroll
      for (int rr = 0; rr < 4; ++rr) {
        const int r = g * 4 + rr;
        float s = fmaf(-2.0f, acc[r], cw[r]);
        if (s <= Tc) {
          int e = (int)((Tc - s) * EQ);
          e = e > 0xFFFFF ? 0xFFFFF : e;
          unsigned key = ((unsigned)e << 12) | (unsigned)(4095 - (ib + g * 8 + rr));
          if (cnt < LCAP) lst[ql][h][cnt] = key;
          ++cnt;
        }
      }
    }
    if (t < 127) {
      *(uint4*)&cst[buf ^ 1][su][sc][0] = st[0];
      *(uint4*)&cst[buf ^ 1][8 + su][sc][0] = st[1];
      *(uint4*)&cst[buf ^ 1][16 + su][sc][0] = st[2];
      *(uint4*)&cst[buf ^ 1][24 + su][sc][0] = st[3];
      if (tid < 32) cn_s[buf ^ 1][tid] = cnreg;
    }
    __syncthreads();
    buf ^= 1;
  }
  lcnt[ql][h] = (unsigned short)cnt;
  __syncthreads();

  if (tid < 128) {
    const int mq = tid;
    const int gq = z * 4096 + qblk * 128 + mq;
    const int c0 = lcnt[mq][0], c1 = lcnt[mq][1];
    const bool over = (c0 > LCAP) || (c1 > LCAP);
    const int n0 = c0 > LCAP ? LCAP : c0;
    const int n1 = c1 > LCAP ? LCAP : c1;
    const int m = n0 + n1;
    unsigned top[10];
#pragma unroll
    for (int j = 0; j < 10; ++j) top[j] = 0u;
    for (int li = 0; li < 2; ++li) {
      const int n = li ? n1 : n0;
      for (int i = 0; i < n; ++i) {
        unsigned key = lst[mq][li][i];
        if (key > top[9]) {
#pragma unroll
          for (int j = 0; j < 10; ++j) {
            bool sw = key > top[j];
            unsigned tv = top[j];
            top[j] = sw ? key : tv;
            key = sw ? tv : key;
          }
        }
      }
    }
    const unsigned e8 = top[8] >> 12, e9 = top[9] >> 12;
    const bool cov = !over && (m >= 9) && (e8 >= GQCOV);
    const bool ok = cov && (m == 9 || (e8 - e9) >= GQGAP);
    const int qg = qblk * 128 + mq;
    const int row = (combo <= 1) ? qg : (N1 + qg);
    const int slot = (combo == 0 || combo == 2) ? 0 : 9;
    const int ioff = (combo == 1 || combo == 2) ? N1 : 0;
    int* dst = nbr + ((size_t)b * NT + row) * NBRS + slot;
    if (ok) {
#pragma unroll
      for (int s = 0; s < 9; ++s)
        dst[s] = (int)(4095u - (top[s] & 0xFFFu)) + ioff;
    } else if (!cov || m > 64) {
      int idx = atomicAdd(&cntg[1], 1);
      listB[idx] = (unsigned)gq;
    } else {
      int idx = atomicAdd(&cntg[0], 1);
      listA[idx] = ((unsigned)m << 16) | (unsigned)gq;
      unsigned short* fp = fbl + (size_t)gq * 64;
      int p = 0;
      for (int i = 0; i < n0; ++i) fp[p++] = (unsigned short)(4095u - (lst[mq][0][i] & 0xFFFu));
      for (int i = 0; i < n1; ++i) fp[p++] = (unsigned short)(4095u - (lst[mq][1][i] & 0xFFFu));
    }
  }
}

// ------- rerank_sl: grid-stride over compacted shortlist queries (wave each)
__global__ __launch_bounds__(256) void rerank_sl_k(const float* __restrict__ xy,
                                                   const float* __restrict__ norms,
                                                   const unsigned short* __restrict__ fbl,
                                                   const unsigned* __restrict__ listA,
                                                   const int* __restrict__ cntg,
                                                   int* __restrict__ nbr) {
  const int lane = threadIdx.x & 63;
  const int wv = threadIdx.x >> 6;
  const int nA = cntg[0];
  for (int i = blockIdx.x * 4 + wv; i < nA; i += gridDim.x * 4) {
    const unsigned ent = listA[i];
    const int gq = (int)(ent & 0xffffu);
    const int m = (int)(ent >> 16);
    const int z = gq >> 12, q = gq & 4095;
    const int b = z >> 2, combo = z & 3;
    const int qoff = (combo <= 1) ? 0 : N1;
    const int coff = (combo == 0 || combo == 3) ? 0 : N1;
    const size_t cq = (size_t)b * NT + coff;
    const int row = (combo <= 1) ? q : (N1 + q);
    const int slot = (combo == 0 || combo == 2) ? 0 : 9;
    const int ioff = (combo == 1 || combo == 2) ? N1 : 0;
    int* dst = nbr + ((size_t)b * NT + row) * NBRS + slot;
    const float* qrow = xy + ((size_t)b * NT + qoff + q) * CH;

    int ci = 0; float de = FLT_MAX;
    if (lane < m) {
      ci = (int)fbl[(size_t)gq * 64 + lane];
      const float* crow = xy + (cq + ci) * CH;
      const float cnv = norms[cq + ci];
      float a0 = 0.f, a1 = 0.f, a2 = 0.f, a3 = 0.f;
#pragma unroll
      for (int k = 0; k < 32; ++k) {
        float4 qv = *(const float4*)(qrow + k * 4);
        float4 cv2 = *(const float4*)(crow + k * 4);
        a0 = fmaf(qv.x, cv2.x, a0); a1 = fmaf(qv.y, cv2.y, a1);
        a2 = fmaf(qv.z, cv2.z, a2); a3 = fmaf(qv.w, cv2.w, a3);
      }
      de = cnv - 2.0f * ((a0 + a1) + (a2 + a3));
    }
    unsigned long long key = ((unsigned long long)mapf(de) << 32) | (unsigned)ci;
    if (lane >= m) key = ~0ull;
    int xr = 0;
#pragma unroll 1
    for (int k = 0; k < m; ++k) {
      unsigned long long kk = __shfl(key, k);
      xr += (kk < key) ? 1 : 0;
    }
    if (lane < m && xr < 9) dst[xr] = ci + ioff;
  }
}

// ------- rerank_fs: grid-stride over full-scan queries (one BLOCK each)
__global__ __launch_bounds__(256) void rerank_fs_k(const float* __restrict__ xy,
                                                   const float* __restrict__ norms,
                                                   const unsigned* __restrict__ listB,
                                                   const int* __restrict__ cntg,
                                                   int* __restrict__ nbr) {
  __shared__ unsigned long long ms[4][576];
  __shared__ unsigned long long wk[36];
  const int tid = threadIdx.x;
  const int lane = tid & 63, wv = tid >> 6;
  const int nB = cntg[1];
  for (int i = blockIdx.x; i < nB; i += gridDim.x) {
    const int gq = (int)listB[i];
    const int z = gq >> 12, q = gq & 4095;
    const int b = z >> 2, combo = z & 3;
    const int qoff = (combo <= 1) ? 0 : N1;
    const int coff = (combo == 0 || combo == 3) ? 0 : N1;
    const size_t cq = (size_t)b * NT + coff;
    const int row = (combo <= 1) ? q : (N1 + q);
    const int slot = (combo == 0 || combo == 2) ? 0 : 9;
    const int ioff = (combo == 1 || combo == 2) ? N1 : 0;
    int* dst = nbr + ((size_t)b * NT + row) * NBRS + slot;
    const float* qrow = xy + ((size_t)b * NT + qoff + q) * CH;

    unsigned long long bl9[9];
#pragma unroll
    for (int j = 0; j < 9; ++j) bl9[j] = ~0ull;
    for (int it = 0; it < 16; ++it) {
      const int cc = (it * 4 + wv) * 64 + lane;
      const float* crow = xy + (cq + cc) * CH;
      float a0 = 0.f, a1 = 0.f, a2 = 0.f, a3 = 0.f;
#pragma unroll
      for (int k = 0; k < 32; ++k) {
        float4 qv = *(const float4*)(qrow + k * 4);
        float4 cv2 = *(const float4*)(crow + k * 4);
        a0 = fmaf(qv.x, cv2.x, a0); a1 = fmaf(qv.y, cv2.y, a1);
        a2 = fmaf(qv.z, cv2.z, a2); a3 = fmaf(qv.w, cv2.w, a3);
      }
      float d2v = norms[cq + cc] - 2.0f * ((a0 + a1) + (a2 + a3));
      unsigned long long key = ((unsigned long long)mapf(d2v) << 32) | (unsigned)cc;
      if (key < bl9[8]) {
#pragma unroll
        for (int jj = 0; jj < 9; ++jj) {
          bool sw = key < bl9[jj];
          unsigned long long tv = bl9[jj];
          bl9[jj] = sw ? key : tv;
          key = sw ? tv : key;
        }
      }
    }
#pragma unroll
    for (int s = 0; s < 9; ++s) ms[wv][lane * 9 + s] = bl9[s];
    int ptr = 0;
    for (int s = 0; s < 9; ++s) {
      unsigned long long hd = ms[wv][lane * 9 + ptr];
      unsigned long long mn = hd;
#pragma unroll
      for (int off = 1; off < 64; off <<= 1) {
        unsigned long long ot = __shfl_xor(mn, off);
        mn = (ot < mn) ? ot : mn;
      }
      unsigned long long wm = __ballot(hd == mn);
      int wl = __ffsll(wm) - 1;
      if (lane == wl) ptr++;
      if (lane == 0) wk[wv * 9 + s] = mn;
    }
    __syncthreads();
    if (wv == 0) {
      unsigned long long key = (lane < 36) ? wk[lane] : ~0ull;
      int xr = 0;
#pragma unroll 1
      for (int k = 0; k < 36; ++k) {
        unsigned long long kk = __shfl(key, k);
        xr += (kk < key) ? 1 : 0;
      }
      if (lane < 36 && xr < 9) dst[xr] = (int)(unsigned)(key & 0xffffffffull) + ioff;
    }
    __syncthreads();
  }
}

// ------- mrconv2: gather+max (VALU/mem) + MFMA 256->128 linear + BN+gelu+res
__global__ __launch_bounds__(256) void mrconv2_k(const float* __restrict__ in,
                                                 const int* __restrict__ nbr,
                                                 const unsigned short* __restrict__ Whi,
                                                 const unsigned short* __restrict__ Wlo,
                                                 const float* __restrict__ bias,
                                                 const float* __restrict__ gam,
                                                 const float* __restrict__ bet,
                                                 const float* __restrict__ mean,
                                                 const float* __restrict__ var,
                                                 float* __restrict__ out) {
  __shared__ float h[32][260];
  const int tid = threadIdx.x;
  const int pt0 = blockIdx.x * 32;
  {
    const int w = tid >> 6, lane = tid & 63;
    for (int pp = 0; pp < 8; ++pp) {
      const int p = w * 8 + pp;
      const int n = pt0 + p;
      const int b = n >> 13;
      const float* frow = in + (size_t)n * CH;
      float2 f2 = *(const float2*)(frow + lane * 2);
      float mx = -FLT_MAX, my = -FLT_MAX;
      const int* nb = nbr + (size_t)n * NBRS;
      for (int j = 0; j < NBRS; ++j) {
        int idx = nb[j];
        const float* vrow = in + ((size_t)b * NT + idx) * CH;
        float2 v2 = *(const float2*)(vrow + lane * 2);
        mx = fmaxf(mx, v2.x - f2.x);
        my = fmaxf(my, v2.y - f2.y);
      }
      h[p][lane * 4 + 0] = f2.x; h[p][lane * 4 + 1] = mx;
      h[p][lane * 4 + 2] = f2.y; h[p][lane * 4 + 3] = my;
    }
  }
  __syncthreads();
  // ---- MFMA linear: K=256, 32 rows (2 tiles of 16), 128 cols.
  // wave w covers colblocks {2w, 2w+1}; A-frags built on the fly from h.
  const int lane = tid & 63, w = tid >> 6;
  const int r16 = lane & 15, kg = lane >> 4;
  f32x4 acc[2][2] = {{{0.f,0.f,0.f,0.f},{0.f,0.f,0.f,0.f}},
                     {{0.f,0.f,0.f,0.f},{0.f,0.f,0.f,0.f}}};
#pragma unroll
  for (int ks = 0; ks < 8; ++ks) {
    s16x8 ah[2], al[2];
#pragma unroll
    for (int rt = 0; rt < 2; ++rt) {
      const float* hp = &h[rt * 16 + r16][(ks * 4 + kg) * 8];
#pragma unroll
      for (int j = 0; j < 8; ++j) {
        float v = hp[j];
        unsigned short hb = f2bf(v);
        float rr = v - bf2f(hb);
        ah[rt][j] = (short)hb;
        al[rt][j] = (short)f2bf(rr);
      }
    }
#pragma unroll
    for (int cbi = 0; cbi < 2; ++cbi) {
      const int o = (w * 2 + cbi) * 16 + r16;
      s16x8 bh2 = *(const s16x8*)(Whi + o * 256 + ks * 32 + kg * 8);
      s16x8 bl2 = *(const s16x8*)(Wlo + o * 256 + ks * 32 + kg * 8);
#pragma unroll
      for (int rt = 0; rt < 2; ++rt) {
        acc[rt][cbi] = __builtin_amdgcn_mfma_f32_16x16x32_bf16(ah[rt], bh2, acc[rt][cbi], 0, 0, 0);
        acc[rt][cbi] = __builtin_amdgcn_mfma_f32_16x16x32_bf16(ah[rt], bl2, acc[rt][cbi], 0, 0, 0);
        acc[rt][cbi] = __builtin_amdgcn_mfma_f32_16x16x32_bf16(al[rt], bh2, acc[rt][cbi], 0, 0, 0);
      }
    }
  }
#pragma unroll
  for (int cbi = 0; cbi < 2; ++cbi) {
    const int o = (w * 2 + cbi) * 16 + r16;
    const float sc = gam[o] / sqrtf(var[o] + 1e-5f);
    const float bs = bias[o], mo = mean[o], be = bet[o];
#pragma unroll
    for (int rt = 0; rt < 2; ++rt) {
#pragma unroll
      for (int rg = 0; rg < 4; ++rg) {
        const int row = rt * 16 + kg * 4 + rg;
        const int n = pt0 + row;
        float bn = (acc[rt][cbi][rg] + bs - mo) * sc + be;
        float gl = gelu_f(bn);
        out[(size_t)n * CH + o] = gl + h[row][2 * o];
      }
    }
  }
}

// --------- fc2: MFMA linear 128->128 + BN + residual. 16 points/block.
__global__ __launch_bounds__(256) void fc2_k(const float* __restrict__ in,
                                             const unsigned short* __restrict__ Whi,
                                             const unsigned short* __restrict__ Wlo,
                                             const float* __restrict__ bias,
                                             const float* __restrict__ gam,
                                             const float* __restrict__ bet,
                                             const float* __restrict__ mean,
                                             const float* __restrict__ var,
                                             const float* __restrict__ xres,
                                             const float* __restrict__ yres,
                                             float* __restrict__ out) {
  __shared__ unsigned short __align__(16) aHi[16][16][8];
  __shared__ unsigned short __align__(16) aLo[16][16][8];
  const int tid = threadIdx.x;
  const int pt0 = blockIdx.x * 16;
  {
    const int row = tid >> 4, ku = tid & 15;
    const float* src = in + (size_t)(pt0 + row) * CH + ku * 8;
    unsigned hw[4], lw[4];
#pragma unroll
    for (int j = 0; j < 4; ++j) {
      float v0 = src[2 * j], v1 = src[2 * j + 1];
      unsigned short h0 = f2bf(v0), h1 = f2bf(v1);
      float r0 = v0 - bf2f(h0), r1 = v1 - bf2f(h1);
      hw[j] = (unsigned)h0 | ((unsigned)h1 << 16);
      lw[j] = (unsigned)f2bf(r0) | ((unsigned)f2bf(r1) << 16);
    }
    *(uint4*)&aHi[ku][row][0] = make_uint4(hw[0], hw[1], hw[2], hw[3]);
    *(uint4*)&aLo[ku][row][0] = make_uint4(lw[0], lw[1], lw[2], lw[3]);
  }
  __syncthreads();
  const int lane = tid & 63, w = tid >> 6;
  const int r16 = lane & 15, kg = lane >> 4;
  f32x4 acc[2] = {{0.f,0.f,0.f,0.f}, {0.f,0.f,0.f,0.f}};
#pragma unroll
  for (int ks = 0; ks < 4; ++ks) {
    s16x8 ah = *(const s16x8*)&aHi[ks * 4 + kg][r16][0];
    s16x8 al = *(const s16x8*)&aLo[ks * 4 + kg][r16][0];
#pragma unroll
    for (int cb = 0; cb < 2; ++cb) {
      const int o = w * 32 + cb * 16 + r16;
      s16x8 bh2 = *(const s16x8*)(Whi + o * 128 + ks * 32 + kg * 8);
      s16x8 bl2 = *(const s16x8*)(Wlo + o * 128 + ks * 32 + kg * 8);
      acc[cb] = __builtin_amdgcn_mfma_f32_16x16x32_bf16(ah, bh2, acc[cb], 0, 0, 0);
      acc[cb] = __builtin_amdgcn_mfma_f32_16x16x32_bf16(ah, bl2, acc[cb], 0, 0, 0);
      acc[cb] = __builtin_amdgcn_mfma_f32_16x16x32_bf16(al, bh2, acc[cb], 0, 0, 0);
    }
  }
#pragma unroll
  for (int cb = 0; cb < 2; ++cb) {
    const int o = w * 32 + cb * 16 + r16;
    const float sc = gam[o] / sqrtf(var[o] + 1e-5f);
    const float bs = bias[o], mo = mean[o], be = bet[o];
#pragma unroll
    for (int rg = 0; rg < 4; ++rg) {
      const int row = kg * 4 + rg;
      const int n = pt0 + row;
      const int b = n >> 13, prow = n & 8191;
      float bn = (acc[cb][rg] + bs - mo) * sc + be;
      float res = (prow < N1) ? xres[((size_t)b * N1 + prow) * CH + o]
                              : yres[((size_t)b * N1 + prow - N1) * CH + o];
      out[(size_t)n * CH + o] = bn + res;
    }
  }
}

// --------- ffn2: MFMA fused 128->512(GELU)->128 + BN + res + mask.
__global__ __launch_bounds__(256) void ffn2_k(const float* __restrict__ u,
                                              const unsigned short* __restrict__ W1hi,
                                              const unsigned short* __restrict__ W1lo,
                                              const float* __restrict__ b1,
                                              const float* __restrict__ g1,
                                              const float* __restrict__ be1,
                                              const float* __restrict__ m1,
                                              const float* __restrict__ v1,
                                              const unsigned short* __restrict__ W2hi,
                                              const unsigned short* __restrict__ W2lo,
                                              const float* __restrict__ b2,
                                              const float* __restrict__ g2,
                                              const float* __restrict__ be2,
                                              const float* __restrict__ m2,
                                              const float* __restrict__ v2,
                                              const float* __restrict__ xmask,
                                              const float* __restrict__ ymask,
                                              float* __restrict__ outbuf) {
  __shared__ unsigned short __align__(16) aHi[16][16][8];
  __shared__ unsigned short __align__(16) aLo[16][16][8];
  __shared__ unsigned short __align__(16) hHi[64][16][8];
  __shared__ unsigned short __align__(16) hLo[64][16][8];
  const int tid = threadIdx.x;
  const int pt0 = blockIdx.x * 16;
  {
    const int row = tid >> 4, ku = tid & 15;
    const float* src = u + (size_t)(pt0 + row) * CH + ku * 8;
    unsigned hw[4], lw[4];
#pragma unroll
    for (int j = 0; j < 4; ++j) {
      float v0 = src[2 * j], v1 = src[2 * j + 1];
      unsigned short h0 = f2bf(v0), h1 = f2bf(v1);
      float r0 = v0 - bf2f(h0), r1 = v1 - bf2f(h1);
      hw[j] = (unsigned)h0 | ((unsigned)h1 << 16);
      lw[j] = (unsigned)f2bf(r0) | ((unsigned)f2bf(r1) << 16);
    }
    *(uint4*)&aHi[ku][row][0] = make_uint4(hw[0], hw[1], hw[2], hw[3]);
    *(uint4*)&aLo[ku][row][0] = make_uint4(lw[0], lw[1], lw[2], lw[3]);
  }
  __syncthreads();
  const int lane = tid & 63, w = tid >> 6;
  const int r16 = lane & 15, kg = lane >> 4;
  {
    f32x4 acc[8];
#pragma unroll
    for (int cb = 0; cb < 8; ++cb) acc[cb] = {0.f, 0.f, 0.f, 0.f};
#pragma unroll
    for (int ks = 0; ks < 4; ++ks) {
      s16x8 ah = *(const s16x8*)&aHi[ks * 4 + kg][r16][0];
      s16x8 al = *(const s16x8*)&aLo[ks * 4 + kg][r16][0];
#pragma unroll
      for (int cb = 0; cb < 8; ++cb) {
        const int o = w * 128 + cb * 16 + r16;
        s16x8 bh2 = *(const s16x8*)(W1hi + o * 128 + ks * 32 + kg * 8);
        s16x8 bl2 = *(const s16x8*)(W1lo + o * 128 + ks * 32 + kg * 8);
        acc[cb] = __builtin_amdgcn_mfma_f32_16x16x32_bf16(ah, bh2, acc[cb], 0, 0, 0);
        acc[cb] = __builtin_amdgcn_mfma_f32_16x16x32_bf16(ah, bl2, acc[cb], 0, 0, 0);
        acc[cb] = __builtin_amdgcn_mfma_f32_16x16x32_bf16(al, bh2, acc[cb], 0, 0, 0);
      }
    }
#pragma unroll
    for (int cb = 0; cb < 8; ++cb) {
      const int o = w * 128 + cb * 16 + r16;
      const float sc = g1[o] / sqrtf(v1[o] + 1e-5f);
      const float bs = b1[o], mo = m1[o], be = be1[o];
#pragma unroll
      for (int rg = 0; rg < 4; ++rg) {
        const int row = kg * 4 + rg;
        float bn = (acc[cb][rg] + bs - mo) * sc + be;
        float gl = gelu_f(bn);
        unsigned short hb = f2bf(gl);
        float rr = gl - bf2f(hb);
        hHi[o >> 3][row][o & 7] = hb;
        hLo[o >> 3][row][o & 7] = f2bf(rr);
      }
    }
  }
  __syncthreads();
  {
    f32x4 acc[2] = {{0.f,0.f,0.f,0.f}, {0.f,0.f,0.f,0.f}};
#pragma unroll
    for (int ks = 0; ks < 16; ++ks) {
      s16x8 ah = *(const s16x8*)&hHi[ks * 4 + kg][r16][0];
      s16x8 al = *(const s16x8*)&hLo[ks * 4 + kg][r16][0];
#pragma unroll
      for (int cb = 0; cb < 2; ++cb) {
        const int o = w * 32 + cb * 16 + r16;
        s16x8 bh2 = *(const s16x8*)(W2hi + o * 512 + ks * 32 + kg * 8);
        s16x8 bl2 = *(const s16x8*)(W2lo + o * 512 + ks * 32 + kg * 8);
        acc[cb] = __builtin_amdgcn_mfma_f32_16x16x32_bf16(ah, bh2, acc[cb], 0, 0, 0);
        acc[cb] = __builtin_amdgcn_mfma_f32_16x16x32_bf16(ah, bl2, acc[cb], 0, 0, 0);
        acc[cb] = __builtin_amdgcn_mfma_f32_16x16x32_bf16(al, bh2, acc[cb], 0, 0, 0);
      }
    }
#pragma unroll
    for (int cb = 0; cb < 2; ++cb) {
      const int o = w * 32 + cb * 16 + r16;
      const float sc = g2[o] / sqrtf(v2[o] + 1e-5f);
      const float bs = b2[o], mo = m2[o], be = be2[o];
#pragma unroll
      for (int rg = 0; rg < 4; ++rg) {
        const int row = kg * 4 + rg;
        const int n = pt0 + row;
        const int b = n >> 13, prow = n & 8191;
        float bn = (acc[cb][rg] + bs - mo) * sc + be;
        float gl = gelu_f(bn);
        float res = u[(size_t)n * CH + o];
        float msk; size_t oidx;
        if (prow < N1) {
          msk = xmask[(size_t)b * N1 + prow];
          oidx = ((size_t)b * N1 + prow) * CH + o;
        } else {
          msk = ymask[(size_t)b * N1 + prow - N1];
          oidx = (size_t)BB * N1 * CH + ((size_t)b * N1 + prow - N1) * CH + o;
        }
        outbuf[oidx] = (gl + res) * msk;
      }
    }
  }
}

// ---------------------------------------------------------------------------
extern "C" void kernel_launch(void* const* d_in, const int* in_sizes, int n_in,
                              void* d_out, int out_size, void* d_ws, size_t ws_size,
                              hipStream_t stream) {
  const float* x  = (const float*)d_in[0];
  const float* y  = (const float*)d_in[1];
  const float* xm = (const float*)d_in[2];
  const float* ym = (const float*)d_in[3];
  const float* mr0W = (const float*)d_in[4];
  const float* mr1W = (const float*)d_in[10];
  const float* fcW  = (const float*)d_in[16];
  const float* f1W  = (const float*)d_in[22];
  const float* f2W  = (const float*)d_in[28];

  char* ws = (char*)d_ws;
  float*          xyA   = (float*)(ws + 0);
  unsigned short* cbt   = (unsigned short*)(ws + 16777216);
  float*          xyB   = (float*)(ws + 16777216);
  float*          norms = (float*)(ws + 33554432);
  int*            cntg  = (int*)(ws + 33685504);
  unsigned*       listA = (unsigned*)(ws + 33689600);
  unsigned*       listB = (unsigned*)(ws + 33951744);
  unsigned short* fbl   = (unsigned short*)(ws + 34213888);  // 8.39 MB
  int*            nbr   = (int*)(ws + 42602496);             // 2.36 MB
  unsigned short* mr0hi = (unsigned short*)(ws + 44961792);  // 64 KB
  unsigned short* mr0lo = (unsigned short*)(ws + 45027328);  // 64 KB
  unsigned short* mr1hi = (unsigned short*)(ws + 45092864);  // 64 KB
  unsigned short* mr1lo = (unsigned short*)(ws + 45158400);  // 64 KB
  unsigned short* fcWhi = (unsigned short*)(ws + 45223936);  // 32 KB
  unsigned short* fcWlo = (unsigned short*)(ws + 45256704);  // 32 KB
  unsigned short* f1hi  = (unsigned short*)(ws + 45289472);  // 128 KB
  unsigned short* f1lo  = (unsigned short*)(ws + 45420544);  // 128 KB
  unsigned short* f2hi  = (unsigned short*)(ws + 45551616);  // 128 KB
  unsigned short* f2lo  = (unsigned short*)(ws + 45682688);  // 128 KB (end 45.81 MB)

  hipMemsetAsync(cntg, 0, 8, stream);

  wsplit_k<<<128, 256, 0, stream>>>(mr0W, mr0hi, mr0lo, 128 * 256);
  wsplit_k<<<128, 256, 0, stream>>>(mr1W, mr1hi, mr1lo, 128 * 256);
  wsplit_k<<<64, 256, 0, stream>>>(fcW, fcWhi, fcWlo, 128 * 128);
  wsplit_k<<<256, 256, 0, stream>>>(f1W, f1hi, f1lo, 512 * 128);
  wsplit_k<<<256, 256, 0, stream>>>(f2W, f2hi, f2lo, 128 * 512);

  norms_concat_k<<<8192, 256, 0, stream>>>(x, y, xyA, norms);
  cbt_k<<<2048, 256, 0, stream>>>(xyA, cbt);
  knn4_k<<<dim3(32, 16), 256, 0, stream>>>(cbt, norms, nbr, cntg, listA, listB, fbl);
  rerank_sl_k<<<256, 256, 0, stream>>>(xyA, norms, fbl, listA, cntg, nbr);
  rerank_fs_k<<<256, 256, 0, stream>>>(xyA, norms, listB, cntg, nbr);

  mrconv2_k<<<1024, 256, 0, stream>>>(xyA, nbr, mr0hi, mr0lo,
      (const float*)d_in[5], (const float*)d_in[6], (const float*)d_in[7],
      (const float*)d_in[8], (const float*)d_in[9], xyB);
  mrconv2_k<<<1024, 256, 0, stream>>>(xyB, nbr, mr1hi, mr1lo,
      (const float*)d_in[11], (const float*)d_in[12], (const float*)d_in[13],
      (const float*)d_in[14], (const float*)d_in[15], xyA);

  fc2_k<<<2048, 256, 0, stream>>>(xyA, fcWhi, fcWlo,
      (const float*)d_in[17], (const float*)d_in[18], (const float*)d_in[19],
      (const float*)d_in[20], (const float*)d_in[21], x, y, xyB);

  ffn2_k<<<2048, 256, 0, stream>>>(xyB,
      f1hi, f1lo, (const float*)d_in[23], (const float*)d_in[24], (const float*)d_in[25],
      (const float*)d_in[26], (const float*)d_in[27],
      f2hi, f2lo, (const float*)d_in[29], (const float*)d_in[30], (const float*)d_in[31],
      (const float*)d_in[32], (const float*)d_in[33],
      xm, ym, (float*)d_out);
}